// Round 1
// baseline (725.781 us; speedup 1.0000x reference)
//
#include <hip/hip_runtime.h>
#include <math.h>

namespace {

constexpr int kN = 4096;   // tokens
constexpr int kC = 1024;   // channels
constexpr int kH = 16;     // heads
constexpr int kD = 64;     // head dim
constexpr int kL = 512;    // window length (8^3)

// ---------------------------------------------------------------------------
// GEMM with bias: C[M][N] = A[M][K] @ B[K][N] + bias[N]   (fp32, 128x128x16)
// 256 threads, 8x8 micro-tile per thread.
// ---------------------------------------------------------------------------
template <int BM, int BN, int BK>
__global__ __launch_bounds__(256) void gemm_bias(
    const float* __restrict__ A, const float* __restrict__ B,
    const float* __restrict__ bias, float* __restrict__ C,
    int M, int N, int K) {
  __shared__ float As[BK][BM];       // transposed A tile: As[k][m]
  __shared__ float Bs[BK][BN + 4];   // row-major B tile (pad 4 floats)

  const int t = threadIdx.x;
  const int tx = t & 15;
  const int ty = t >> 4;
  const int row0 = blockIdx.y * BM;
  const int col0 = blockIdx.x * BN;

  float acc[8][8];
#pragma unroll
  for (int i = 0; i < 8; ++i)
#pragma unroll
    for (int j = 0; j < 8; ++j) acc[i][j] = 0.f;

  const int ar = t >> 2;        // 0..63  A row within half-tile
  const int ak = (t & 3) * 4;   // 0,4,8,12
  const int bk = t >> 5;        // 0..7
  const int bn = (t & 31) * 4;  // 0..124

  for (int k0 = 0; k0 < K; k0 += BK) {
    // A tile -> LDS (transposed)
#pragma unroll
    for (int i = 0; i < BM / 64; ++i) {
      const int rr = ar + i * 64;
      const float4 v =
          *(const float4*)&A[(size_t)(row0 + rr) * K + (k0 + ak)];
      As[ak + 0][rr] = v.x;
      As[ak + 1][rr] = v.y;
      As[ak + 2][rr] = v.z;
      As[ak + 3][rr] = v.w;
    }
    // B tile -> LDS
#pragma unroll
    for (int i = 0; i < BK / 8; ++i) {
      const int kr = bk + i * 8;
      *(float4*)&Bs[kr][bn] =
          *(const float4*)&B[(size_t)(k0 + kr) * N + (col0 + bn)];
    }
    __syncthreads();

#pragma unroll
    for (int kk = 0; kk < BK; ++kk) {
      float a[8], b[8];
      *(float4*)&a[0] = *(const float4*)&As[kk][ty * 8];
      *(float4*)&a[4] = *(const float4*)&As[kk][ty * 8 + 4];
      *(float4*)&b[0] = *(const float4*)&Bs[kk][tx * 8];
      *(float4*)&b[4] = *(const float4*)&Bs[kk][tx * 8 + 4];
#pragma unroll
      for (int i = 0; i < 8; ++i)
#pragma unroll
        for (int j = 0; j < 8; ++j) acc[i][j] = fmaf(a[i], b[j], acc[i][j]);
    }
    __syncthreads();
  }

#pragma unroll
  for (int i = 0; i < 8; ++i) {
    const int r = row0 + ty * 8 + i;
#pragma unroll
    for (int j = 0; j < 8; j += 4) {
      const int c = col0 + tx * 8 + j;
      const float4 bv = *(const float4*)&bias[c];
      float4 o;
      o.x = acc[i][j + 0] + bv.x;
      o.y = acc[i][j + 1] + bv.y;
      o.z = acc[i][j + 2] + bv.z;
      o.w = acc[i][j + 3] + bv.w;
      *(float4*)&C[(size_t)r * N + c] = o;
    }
  }
}

// ---------------------------------------------------------------------------
// Fused per-head RMS-norm + RoPE + window permutation.
// qkv[N][3*C] -> qw/kw/vw in [W=8][H=16][L=512][D=64] layout.
// One wave per token (4 tokens / 256-thread block). Thread: (head h, quad of
// 16 channels). Window rank for the stable argsort is analytic:
// p = (z&7)*64 + (y&7)*8 + (x&7) because original index order within a
// window is lexicographic in local coords.
// ---------------------------------------------------------------------------
__global__ __launch_bounds__(256) void post_qkv(
    const float* __restrict__ qkv, const int* __restrict__ coords,
    const float* __restrict__ qg, const float* __restrict__ kg,
    float* __restrict__ qw, float* __restrict__ kw, float* __restrict__ vw) {
  const int token = blockIdx.x * 4 + (threadIdx.x >> 6);
  const int t = threadIdx.x & 63;
  const int h = t >> 2;
  const int quad = t & 3;
  const int d0 = quad * 16;

  const float* base = qkv + (size_t)token * (3 * kC) + h * kD + d0;
  float qv[16], kv[16], vv[16];
#pragma unroll
  for (int i = 0; i < 16; i += 4) {
    *(float4*)&qv[i] = *(const float4*)&base[i];
    *(float4*)&kv[i] = *(const float4*)&base[kC + i];
    *(float4*)&vv[i] = *(const float4*)&base[2 * kC + i];
  }

  float sq = 0.f, sk = 0.f;
#pragma unroll
  for (int i = 0; i < 16; ++i) {
    sq += qv[i] * qv[i];
    sk += kv[i] * kv[i];
  }
  // reduce over the 4 lanes that share this head
  sq += __shfl_xor(sq, 1);
  sq += __shfl_xor(sq, 2);
  sk += __shfl_xor(sk, 1);
  sk += __shfl_xor(sk, 2);
  const float qs = 8.0f / fmaxf(sqrtf(sq), 1e-12f);  // sqrt(D)=8
  const float ks = 8.0f / fmaxf(sqrtf(sk), 1e-12f);

#pragma unroll
  for (int i = 0; i < 16; ++i) {
    qv[i] *= qs * qg[h * kD + d0 + i];
    kv[i] *= ks * kg[h * kD + d0 + i];
  }

  const int cz = coords[token * 4 + 1];
  const int cy = coords[token * 4 + 2];
  const int cx = coords[token * 4 + 3];

#pragma unroll
  for (int jj = 0; jj < 8; ++jj) {
    const int j = quad * 8 + jj;  // rope pair index 0..31
    float ang = 0.f;
    if (j < 30) {
      const int axis = j / 10;
      const int f = j - axis * 10;
      const float coord = (float)(axis == 0 ? cz : (axis == 1 ? cy : cx));
      const float freq = expf(-(float)f * 0.92103403719761836f);  // ln(1e4)/10
      ang = coord * freq;
    }
    float sn, cs;
    sincosf(ang, &sn, &cs);
    const float qre = qv[2 * jj], qim = qv[2 * jj + 1];
    qv[2 * jj + 0] = qre * cs - qim * sn;
    qv[2 * jj + 1] = qre * sn + qim * cs;
    const float kre = kv[2 * jj], kim = kv[2 * jj + 1];
    kv[2 * jj + 0] = kre * cs - kim * sn;
    kv[2 * jj + 1] = kre * sn + kim * cs;
  }

  const int w = ((cz >> 3) * 2 + (cy >> 3)) * 2 + (cx >> 3);
  const int p = ((cz & 7) * 8 + (cy & 7)) * 8 + (cx & 7);
  const size_t outIdx = (((size_t)(w * kH + h) * kL) + p) * kD + d0;
  float* qo = qw + outIdx;
  float* ko = kw + outIdx;
  float* vo = vw + outIdx;
#pragma unroll
  for (int i = 0; i < 16; i += 4) {
    *(float4*)&qo[i] = *(const float4*)&qv[i];
    *(float4*)&ko[i] = *(const float4*)&kv[i];
    *(float4*)&vo[i] = *(const float4*)&vv[i];
  }
}

// ---------------------------------------------------------------------------
// Windowed attention, flash-style. One block = (window w, head h, 64 q rows).
// grid = 8 q-tiles * 16 heads * 8 windows = 1024 blocks, 256 threads.
// Thread (ty,tx) owns a 4x4 tile of S / O. Online softmax across 8 k-tiles.
// Writes O directly back to token order (inverse permutation analytic).
// ---------------------------------------------------------------------------
__global__ __launch_bounds__(256) void attn(
    const float* __restrict__ qw, const float* __restrict__ kw,
    const float* __restrict__ vw, float* __restrict__ obuf) {
  constexpr int PAD = 68;
  __shared__ float Qs[64][PAD];  // Qs[d][r]
  __shared__ float Ks[64][PAD];  // Ks[d][c] for QK^T, reused as Vs[c][d] for PV
  __shared__ float Ps[64][PAD];  // Ps[c][r]

  const int bid = blockIdx.x;
  const int qt = bid & 7;
  const int h = (bid >> 3) & 15;
  const int w = bid >> 7;
  const int t = threadIdx.x;
  const int tx = t & 15;
  const int ty = t >> 4;

  const size_t whbase = (size_t)(w * kH + h) * kL * kD;
  const float* qb = qw + whbase + (size_t)qt * 64 * kD;
  const float* kb = kw + whbase;
  const float* vb = vw + whbase;

  // stage Q transposed
  {
    const int r = t >> 2;
    const int dd = (t & 3) * 16;
#pragma unroll
    for (int ii = 0; ii < 4; ++ii) {
      const float4 v = *(const float4*)&qb[r * kD + dd + ii * 4];
      Qs[dd + ii * 4 + 0][r] = v.x;
      Qs[dd + ii * 4 + 1][r] = v.y;
      Qs[dd + ii * 4 + 2][r] = v.z;
      Qs[dd + ii * 4 + 3][r] = v.w;
    }
  }

  float accO[4][4];
  float m[4], l[4];
#pragma unroll
  for (int i = 0; i < 4; ++i) {
    m[i] = -1e30f;
    l[i] = 0.f;
#pragma unroll
    for (int j = 0; j < 4; ++j) accO[i][j] = 0.f;
  }

  for (int kt = 0; kt < 8; ++kt) {
    __syncthreads();  // previous PV done with Ks(as V) and Ps; Q staged (kt=0)
    // stage K tile transposed: Ks[d][c]
    {
      const int c = t >> 2;
      const int dd = (t & 3) * 16;
#pragma unroll
      for (int ii = 0; ii < 4; ++ii) {
        const float4 v = *(const float4*)&kb[(kt * 64 + c) * kD + dd + ii * 4];
        Ks[dd + ii * 4 + 0][c] = v.x;
        Ks[dd + ii * 4 + 1][c] = v.y;
        Ks[dd + ii * 4 + 2][c] = v.z;
        Ks[dd + ii * 4 + 3][c] = v.w;
      }
    }
    __syncthreads();

    // S = Q K^T  (4x4 per thread)
    float s[4][4];
#pragma unroll
    for (int i = 0; i < 4; ++i)
#pragma unroll
      for (int j = 0; j < 4; ++j) s[i][j] = 0.f;
#pragma unroll 8
    for (int d = 0; d < 64; ++d) {
      float a[4], b[4];
      *(float4*)a = *(const float4*)&Qs[d][ty * 4];
      *(float4*)b = *(const float4*)&Ks[d][tx * 4];
#pragma unroll
      for (int i = 0; i < 4; ++i)
#pragma unroll
        for (int j = 0; j < 4; ++j) s[i][j] = fmaf(a[i], b[j], s[i][j]);
    }

    // online softmax update + stage P
#pragma unroll
    for (int i = 0; i < 4; ++i) {
#pragma unroll
      for (int j = 0; j < 4; ++j) s[i][j] *= 0.125f;  // 1/sqrt(64)
      float rmax = fmaxf(fmaxf(s[i][0], s[i][1]), fmaxf(s[i][2], s[i][3]));
      rmax = fmaxf(rmax, __shfl_xor(rmax, 1));
      rmax = fmaxf(rmax, __shfl_xor(rmax, 2));
      rmax = fmaxf(rmax, __shfl_xor(rmax, 4));
      rmax = fmaxf(rmax, __shfl_xor(rmax, 8));
      const float mn = fmaxf(m[i], rmax);
      const float corr = expf(m[i] - mn);
      float p0 = expf(s[i][0] - mn);
      float p1 = expf(s[i][1] - mn);
      float p2 = expf(s[i][2] - mn);
      float p3 = expf(s[i][3] - mn);
      float rs = p0 + p1 + p2 + p3;
      rs += __shfl_xor(rs, 1);
      rs += __shfl_xor(rs, 2);
      rs += __shfl_xor(rs, 4);
      rs += __shfl_xor(rs, 8);
      l[i] = l[i] * corr + rs;
      m[i] = mn;
#pragma unroll
      for (int j = 0; j < 4; ++j) accO[i][j] *= corr;
      Ps[tx * 4 + 0][ty * 4 + i] = p0;
      Ps[tx * 4 + 1][ty * 4 + i] = p1;
      Ps[tx * 4 + 2][ty * 4 + i] = p2;
      Ps[tx * 4 + 3][ty * 4 + i] = p3;
    }
    __syncthreads();  // S-phase reads of Ks done; P visible next barrier

    // stage V tile into Ks buffer: Vs[c][d]
    {
      const int c = t >> 2;
      const int dd = (t & 3) * 16;
#pragma unroll
      for (int ii = 0; ii < 4; ++ii) {
        *(float4*)&Ks[c][dd + ii * 4] =
            *(const float4*)&vb[(kt * 64 + c) * kD + dd + ii * 4];
      }
    }
    __syncthreads();

    // O += P V  (4x4 per thread)
#pragma unroll 8
    for (int c = 0; c < 64; ++c) {
      float a[4], b[4];
      *(float4*)a = *(const float4*)&Ps[c][ty * 4];
      *(float4*)b = *(const float4*)&Ks[c][tx * 4];
#pragma unroll
      for (int i = 0; i < 4; ++i)
#pragma unroll
        for (int j = 0; j < 4; ++j) accO[i][j] = fmaf(a[i], b[j], accO[i][j]);
    }
  }

  // epilogue: divide by l, scatter to original token order
  const int wz = w >> 2, wy = (w >> 1) & 1, wx = w & 1;
#pragma unroll
  for (int i = 0; i < 4; ++i) {
    const int pg = qt * 64 + ty * 4 + i;
    const int pz = pg >> 6, py = (pg >> 3) & 7, px = pg & 7;
    const int z = wz * 8 + pz, y = wy * 8 + py, x = wx * 8 + px;
    const int n = (z * 16 + y) * 16 + x;
    const float inv = 1.0f / l[i];
    float4 o;
    o.x = accO[i][0] * inv;
    o.y = accO[i][1] * inv;
    o.z = accO[i][2] * inv;
    o.w = accO[i][3] * inv;
    *(float4*)&obuf[(size_t)n * kC + h * kD + tx * 4] = o;
  }
}

}  // namespace

extern "C" void kernel_launch(void* const* d_in, const int* in_sizes, int n_in,
                              void* d_out, int out_size, void* d_ws,
                              size_t ws_size, hipStream_t stream) {
  const float* x = (const float*)d_in[0];
  const int* coords = (const int*)d_in[1];
  const float* w_qkv = (const float*)d_in[2];
  const float* b_qkv = (const float*)d_in[3];
  const float* qg = (const float*)d_in[4];
  const float* kg = (const float*)d_in[5];
  const float* w_out = (const float*)d_in[6];
  const float* b_out = (const float*)d_in[7];
  float* out = (float*)d_out;

  char* ws = (char*)d_ws;
  float* qkv = (float*)ws;                                  // 4096*3072 f32
  float* qw = (float*)(ws + (size_t)kN * 3 * kC * sizeof(float));
  float* kw = qw + (size_t)kN * kC;
  float* vw = kw + (size_t)kN * kC;
  float* obuf = qkv;  // alias: qkv dead after post_qkv

  // 1) QKV projection
  gemm_bias<128, 128, 16><<<dim3(3 * kC / 128, kN / 128), 256, 0, stream>>>(
      x, w_qkv, b_qkv, qkv, kN, 3 * kC, kC);
  // 2) RMS-norm + RoPE + window permute
  post_qkv<<<dim3(kN / 4), 256, 0, stream>>>(qkv, coords, qg, kg, qw, kw, vw);
  // 3) windowed attention (writes in original token order)
  attn<<<dim3(8 * kH * 8), 256, 0, stream>>>(qw, kw, vw, obuf);
  // 4) output projection
  gemm_bias<128, 128, 16><<<dim3(kC / 128, kN / 128), 256, 0, stream>>>(
      obuf, w_out, b_out, out, kN, kC, kC);
}

// Round 4
// 429.507 us; speedup vs baseline: 1.6898x; 1.6898x over previous
//
#include <hip/hip_runtime.h>
#include <math.h>

namespace {

typedef unsigned short ushort_t;
typedef __attribute__((ext_vector_type(8))) short bf16x8;
typedef __attribute__((ext_vector_type(8))) unsigned short u16x8;
typedef __attribute__((ext_vector_type(4))) unsigned short u16x4;
typedef __attribute__((ext_vector_type(4))) float f32x4;

constexpr int kN = 4096;   // tokens
constexpr int kC = 1024;   // channels
constexpr int kH = 16;     // heads
constexpr int kD = 64;     // head dim
constexpr int kL = 512;    // window length (8^3)

__device__ __forceinline__ ushort_t f2bf(float f) {
  unsigned u = __float_as_uint(f);
  unsigned r = (u + 0x7FFFu + ((u >> 16) & 1u)) >> 16;
  return (ushort_t)r;
}
__device__ __forceinline__ float bf2f(ushort_t h) {
  return __uint_as_float((unsigned)h << 16);
}

__device__ __forceinline__ void gload16(const void* g, void* l) {
  __builtin_amdgcn_global_load_lds(
      (const __attribute__((address_space(1))) unsigned int*)g,
      (__attribute__((address_space(3))) unsigned int*)l, 16, 0, 0);
}

// ---------------------------------------------------------------------------
// Split fp32 [M][K] row-major -> packed hi/lo bf16 [(K/8)][M][8] (k-major).
// 64x64 tile via LDS transpose; coalesced reads and writes.
// ---------------------------------------------------------------------------
__global__ __launch_bounds__(256) void split_pack_rows(
    const float* __restrict__ src, ushort_t* __restrict__ hi,
    ushort_t* __restrict__ lo, int M, int K) {
  __shared__ __align__(16) ushort_t Th[64][72];
  __shared__ __align__(16) ushort_t Tl[64][72];
  const int t = threadIdx.x;
  const int m0 = blockIdx.x * 64, k0 = blockIdx.y * 64;
#pragma unroll
  for (int it = 0; it < 4; ++it) {
    const int slot = it * 256 + t;  // 0..1023
    const int m = slot >> 4;
    const int k4 = (slot & 15) * 4;
    const float4 v = *(const float4*)&src[(size_t)(m0 + m) * K + k0 + k4];
    float vv[4] = {v.x, v.y, v.z, v.w};
#pragma unroll
    for (int j = 0; j < 4; ++j) {
      const ushort_t hb = f2bf(vv[j]);
      Th[m][k4 + j] = hb;
      Tl[m][k4 + j] = f2bf(vv[j] - bf2f(hb));
    }
  }
  __syncthreads();
#pragma unroll
  for (int it = 0; it < 2; ++it) {
    const int slot = it * 256 + t;  // 0..511
    const int kcl = slot >> 6;      // 0..7
    const int m = slot & 63;
    const size_t o = ((size_t)(blockIdx.y * 8 + kcl) * M + m0 + m) * 8;
    *(u16x8*)&hi[o] = *(const u16x8*)&Th[m][kcl * 8];
    *(u16x8*)&lo[o] = *(const u16x8*)&Tl[m][kcl * 8];
  }
}

// ---------------------------------------------------------------------------
// Split fp32 [K][N] (k-major already) -> packed hi/lo bf16 [(K/8)][N][8].
// grid (N/256, K/8). Coalesced reads & writes.
// ---------------------------------------------------------------------------
__global__ __launch_bounds__(256) void split_pack_w(
    const float* __restrict__ src, ushort_t* __restrict__ hi,
    ushort_t* __restrict__ lo, int K, int N) {
  const int n = blockIdx.x * 256 + threadIdx.x;
  const int kcg = blockIdx.y;
  u16x8 h, l;
#pragma unroll
  for (int j = 0; j < 8; ++j) {
    const float v = src[(size_t)(kcg * 8 + j) * N + n];
    const ushort_t hb = f2bf(v);
    h[j] = hb;
    l[j] = f2bf(v - bf2f(hb));
  }
  const size_t o = ((size_t)kcg * N + n) * 8;
  *(u16x8*)&hi[o] = h;
  *(u16x8*)&lo[o] = l;
}

// ---------------------------------------------------------------------------
// Split-bf16 MFMA GEMM: C[M][N] = Ah@Bh + Ah@Bl + Al@Bh + bias.
// A,B packed k-major [(K/8)][rows-or-cols][8] bf16. 128x128 tile, BK=32,
// 4 waves (2x2), each wave 64x64 via 4x4 frags of mfma_f32_16x16x32_bf16.
// global_load_lds width-16 staging, conflict-free LDS layout.
// ---------------------------------------------------------------------------
__global__ __launch_bounds__(256) void gemm_mfma(
    const ushort_t* __restrict__ Ah, const ushort_t* __restrict__ Al,
    const ushort_t* __restrict__ Bh, const ushort_t* __restrict__ Bl,
    const float* __restrict__ bias, float* __restrict__ C, int M, int N,
    int K) {
  __shared__ __align__(16) ushort_t As[2][4][128][8];  // [hl][kc][m][8]
  __shared__ __align__(16) ushort_t Bs[2][4][128][8];  // [hl][kc][n][8]

  const int t = threadIdx.x;
  const int lane = t & 63;
  const int wid = t >> 6;
  const int wr = wid >> 1, wc = wid & 1;
  const int l15 = lane & 15, lk = lane >> 4;
  const int row0 = blockIdx.y * 128, col0 = blockIdx.x * 128;

  f32x4 acc[4][4];
#pragma unroll
  for (int i = 0; i < 4; ++i)
#pragma unroll
    for (int j = 0; j < 4; ++j) acc[i][j] = (f32x4){0.f, 0.f, 0.f, 0.f};

  for (int k0 = 0; k0 < K; k0 += 32) {
    const int kq = k0 >> 3;
    // stage 32 KB: A hi/lo + B hi/lo, 8 x 16B per thread
#pragma unroll
    for (int s = 0; s < 4; ++s) {
      const int li = s * 256 + t;
      const int kc = (li >> 7) & 3;
      const int r = li & 127;
      const size_t goff = ((size_t)(kq + kc));
      const ushort_t* Asrc = ((li >> 9) ? Al : Ah) + (goff * M + row0 + r) * 8;
      const ushort_t* Bsrc = ((li >> 9) ? Bl : Bh) + (goff * N + col0 + r) * 8;
      char* adst = (char*)(&As[0][0][0][0]) + (size_t)(s * 256 + wid * 64) * 16;
      char* bdst = (char*)(&Bs[0][0][0][0]) + (size_t)(s * 256 + wid * 64) * 16;
      gload16(Asrc, adst);
      gload16(Bsrc, bdst);
    }
    __syncthreads();

    bf16x8 af[2][4], bf[2][4];
#pragma unroll
    for (int hl = 0; hl < 2; ++hl)
#pragma unroll
      for (int f = 0; f < 4; ++f) {
        af[hl][f] = *(const bf16x8*)&As[hl][lk][wr * 64 + f * 16 + l15][0];
        bf[hl][f] = *(const bf16x8*)&Bs[hl][lk][wc * 64 + f * 16 + l15][0];
      }
#pragma unroll
    for (int mf = 0; mf < 4; ++mf)
#pragma unroll
      for (int nf = 0; nf < 4; ++nf) {
        acc[mf][nf] = __builtin_amdgcn_mfma_f32_16x16x32_bf16(
            af[0][mf], bf[0][nf], acc[mf][nf], 0, 0, 0);
        acc[mf][nf] = __builtin_amdgcn_mfma_f32_16x16x32_bf16(
            af[0][mf], bf[1][nf], acc[mf][nf], 0, 0, 0);
        acc[mf][nf] = __builtin_amdgcn_mfma_f32_16x16x32_bf16(
            af[1][mf], bf[0][nf], acc[mf][nf], 0, 0, 0);
      }
    __syncthreads();
  }

#pragma unroll
  for (int mf = 0; mf < 4; ++mf)
#pragma unroll
    for (int nf = 0; nf < 4; ++nf) {
      const int col = col0 + wc * 64 + nf * 16 + l15;
      const float bv = bias[col];
#pragma unroll
      for (int r = 0; r < 4; ++r) {
        const int row = row0 + wr * 64 + mf * 16 + lk * 4 + r;
        C[(size_t)row * N + col] = acc[mf][nf][r] + bv;
      }
    }
}

// ---------------------------------------------------------------------------
// Fused per-head RMS-norm + RoPE + window permutation (fp32).
// ---------------------------------------------------------------------------
__global__ __launch_bounds__(256) void post_qkv(
    const float* __restrict__ qkv, const int* __restrict__ coords,
    const float* __restrict__ qg, const float* __restrict__ kg,
    float* __restrict__ qw, float* __restrict__ kw, float* __restrict__ vw) {
  const int token = blockIdx.x * 4 + (threadIdx.x >> 6);
  const int t = threadIdx.x & 63;
  const int h = t >> 2;
  const int quad = t & 3;
  const int d0 = quad * 16;

  const float* base = qkv + (size_t)token * (3 * kC) + h * kD + d0;
  float qv[16], kv[16], vv[16];
#pragma unroll
  for (int i = 0; i < 16; i += 4) {
    *(float4*)&qv[i] = *(const float4*)&base[i];
    *(float4*)&kv[i] = *(const float4*)&base[kC + i];
    *(float4*)&vv[i] = *(const float4*)&base[2 * kC + i];
  }

  float sq = 0.f, sk = 0.f;
#pragma unroll
  for (int i = 0; i < 16; ++i) {
    sq += qv[i] * qv[i];
    sk += kv[i] * kv[i];
  }
  sq += __shfl_xor(sq, 1);
  sq += __shfl_xor(sq, 2);
  sk += __shfl_xor(sk, 1);
  sk += __shfl_xor(sk, 2);
  const float qs = 8.0f / fmaxf(sqrtf(sq), 1e-12f);
  const float ks = 8.0f / fmaxf(sqrtf(sk), 1e-12f);

#pragma unroll
  for (int i = 0; i < 16; ++i) {
    qv[i] *= qs * qg[h * kD + d0 + i];
    kv[i] *= ks * kg[h * kD + d0 + i];
  }

  const int cz = coords[token * 4 + 1];
  const int cy = coords[token * 4 + 2];
  const int cx = coords[token * 4 + 3];

#pragma unroll
  for (int jj = 0; jj < 8; ++jj) {
    const int j = quad * 8 + jj;
    float ang = 0.f;
    if (j < 30) {
      const int axis = j / 10;
      const int f = j - axis * 10;
      const float coord = (float)(axis == 0 ? cz : (axis == 1 ? cy : cx));
      const float freq = expf(-(float)f * 0.92103403719761836f);
      ang = coord * freq;
    }
    float sn, cs;
    sincosf(ang, &sn, &cs);
    const float qre = qv[2 * jj], qim = qv[2 * jj + 1];
    qv[2 * jj + 0] = qre * cs - qim * sn;
    qv[2 * jj + 1] = qre * sn + qim * cs;
    const float kre = kv[2 * jj], kim = kv[2 * jj + 1];
    kv[2 * jj + 0] = kre * cs - kim * sn;
    kv[2 * jj + 1] = kre * sn + kim * cs;
  }

  const int w = ((cz >> 3) * 2 + (cy >> 3)) * 2 + (cx >> 3);
  const int p = ((cz & 7) * 8 + (cy & 7)) * 8 + (cx & 7);
  const size_t outIdx = (((size_t)(w * kH + h) * kL) + p) * kD + d0;
  float* qo = qw + outIdx;
  float* ko = kw + outIdx;
  float* vo = vw + outIdx;
#pragma unroll
  for (int i = 0; i < 16; i += 4) {
    *(float4*)&qo[i] = *(const float4*)&qv[i];
    *(float4*)&ko[i] = *(const float4*)&kv[i];
    *(float4*)&vo[i] = *(const float4*)&vv[i];
  }
}

// ---------------------------------------------------------------------------
// Windowed attention, flash-style fp32. Epilogue writes hi/lo bf16 packed
// k-major [(C/8)][N][8] for the MFMA output-projection GEMM.
// ---------------------------------------------------------------------------
__global__ __launch_bounds__(256) void attn(
    const float* __restrict__ qw, const float* __restrict__ kw,
    const float* __restrict__ vw, ushort_t* __restrict__ obh,
    ushort_t* __restrict__ obl) {
  constexpr int PAD = 68;
  __shared__ float Qs[64][PAD];
  __shared__ float Ks[64][PAD];
  __shared__ float Ps[64][PAD];

  const int bid = blockIdx.x;
  const int qt = bid & 7;
  const int h = (bid >> 3) & 15;
  const int w = bid >> 7;
  const int t = threadIdx.x;
  const int tx = t & 15;
  const int ty = t >> 4;

  const size_t whbase = (size_t)(w * kH + h) * kL * kD;
  const float* qb = qw + whbase + (size_t)qt * 64 * kD;
  const float* kb = kw + whbase;
  const float* vb = vw + whbase;

  {
    const int r = t >> 2;
    const int dd = (t & 3) * 16;
#pragma unroll
    for (int ii = 0; ii < 4; ++ii) {
      const float4 v = *(const float4*)&qb[r * kD + dd + ii * 4];
      Qs[dd + ii * 4 + 0][r] = v.x;
      Qs[dd + ii * 4 + 1][r] = v.y;
      Qs[dd + ii * 4 + 2][r] = v.z;
      Qs[dd + ii * 4 + 3][r] = v.w;
    }
  }

  float accO[4][4];
  float m[4], l[4];
#pragma unroll
  for (int i = 0; i < 4; ++i) {
    m[i] = -1e30f;
    l[i] = 0.f;
#pragma unroll
    for (int j = 0; j < 4; ++j) accO[i][j] = 0.f;
  }

  for (int kt = 0; kt < 8; ++kt) {
    __syncthreads();
    {
      const int c = t >> 2;
      const int dd = (t & 3) * 16;
#pragma unroll
      for (int ii = 0; ii < 4; ++ii) {
        const float4 v = *(const float4*)&kb[(kt * 64 + c) * kD + dd + ii * 4];
        Ks[dd + ii * 4 + 0][c] = v.x;
        Ks[dd + ii * 4 + 1][c] = v.y;
        Ks[dd + ii * 4 + 2][c] = v.z;
        Ks[dd + ii * 4 + 3][c] = v.w;
      }
    }
    __syncthreads();

    float s[4][4];
#pragma unroll
    for (int i = 0; i < 4; ++i)
#pragma unroll
      for (int j = 0; j < 4; ++j) s[i][j] = 0.f;
#pragma unroll 8
    for (int d = 0; d < 64; ++d) {
      float a[4], b[4];
      *(float4*)a = *(const float4*)&Qs[d][ty * 4];
      *(float4*)b = *(const float4*)&Ks[d][tx * 4];
#pragma unroll
      for (int i = 0; i < 4; ++i)
#pragma unroll
        for (int j = 0; j < 4; ++j) s[i][j] = fmaf(a[i], b[j], s[i][j]);
    }

#pragma unroll
    for (int i = 0; i < 4; ++i) {
#pragma unroll
      for (int j = 0; j < 4; ++j) s[i][j] *= 0.125f;
      float rmax = fmaxf(fmaxf(s[i][0], s[i][1]), fmaxf(s[i][2], s[i][3]));
      rmax = fmaxf(rmax, __shfl_xor(rmax, 1));
      rmax = fmaxf(rmax, __shfl_xor(rmax, 2));
      rmax = fmaxf(rmax, __shfl_xor(rmax, 4));
      rmax = fmaxf(rmax, __shfl_xor(rmax, 8));
      const float mn = fmaxf(m[i], rmax);
      const float corr = expf(m[i] - mn);
      float p0 = expf(s[i][0] - mn);
      float p1 = expf(s[i][1] - mn);
      float p2 = expf(s[i][2] - mn);
      float p3 = expf(s[i][3] - mn);
      float rs = p0 + p1 + p2 + p3;
      rs += __shfl_xor(rs, 1);
      rs += __shfl_xor(rs, 2);
      rs += __shfl_xor(rs, 4);
      rs += __shfl_xor(rs, 8);
      l[i] = l[i] * corr + rs;
      m[i] = mn;
#pragma unroll
      for (int j = 0; j < 4; ++j) accO[i][j] *= corr;
      Ps[tx * 4 + 0][ty * 4 + i] = p0;
      Ps[tx * 4 + 1][ty * 4 + i] = p1;
      Ps[tx * 4 + 2][ty * 4 + i] = p2;
      Ps[tx * 4 + 3][ty * 4 + i] = p3;
    }
    __syncthreads();

    {
      const int c = t >> 2;
      const int dd = (t & 3) * 16;
#pragma unroll
      for (int ii = 0; ii < 4; ++ii) {
        *(float4*)&Ks[c][dd + ii * 4] =
            *(const float4*)&vb[(kt * 64 + c) * kD + dd + ii * 4];
      }
    }
    __syncthreads();

#pragma unroll 8
    for (int c = 0; c < 64; ++c) {
      float a[4], b[4];
      *(float4*)a = *(const float4*)&Ps[c][ty * 4];
      *(float4*)b = *(const float4*)&Ks[c][tx * 4];
#pragma unroll
      for (int i = 0; i < 4; ++i)
#pragma unroll
        for (int j = 0; j < 4; ++j) accO[i][j] = fmaf(a[i], b[j], accO[i][j]);
    }
  }

  // epilogue: divide by l, split hi/lo bf16, scatter packed k-major
  const int wz = w >> 2, wy = (w >> 1) & 1, wx = w & 1;
  const int c0 = h * kD + tx * 4;
#pragma unroll
  for (int i = 0; i < 4; ++i) {
    const int pg = qt * 64 + ty * 4 + i;
    const int pz = pg >> 6, py = (pg >> 3) & 7, px = pg & 7;
    const int z = wz * 8 + pz, y = wy * 8 + py, x = wx * 8 + px;
    const int n = (z * 16 + y) * 16 + x;
    const float inv = 1.0f / l[i];
    u16x4 hv, lv;
#pragma unroll
    for (int j = 0; j < 4; ++j) {
      const float v = accO[i][j] * inv;
      const ushort_t hb = f2bf(v);
      hv[j] = hb;
      lv[j] = f2bf(v - bf2f(hb));
    }
    const size_t o = ((size_t)(c0 >> 3) * kN + n) * 8 + (c0 & 7);
    *(u16x4*)&obh[o] = hv;
    *(u16x4*)&obl[o] = lv;
  }
}

}  // namespace

extern "C" void kernel_launch(void* const* d_in, const int* in_sizes, int n_in,
                              void* d_out, int out_size, void* d_ws,
                              size_t ws_size, hipStream_t stream) {
  const float* x = (const float*)d_in[0];
  const int* coords = (const int*)d_in[1];
  const float* w_qkv = (const float*)d_in[2];
  const float* b_qkv = (const float*)d_in[3];
  const float* qg = (const float*)d_in[4];
  const float* kg = (const float*)d_in[5];
  const float* w_out = (const float*)d_in[6];
  const float* b_out = (const float*)d_in[7];
  float* out = (float*)d_out;

  char* ws8 = (char*)d_ws;
  // region 0: qkv fp32 (50.33 MB); later reused for obuf hi/lo + w_out pack
  float* qkv = (float*)ws8;
  ushort_t* obh = (ushort_t*)ws8;
  ushort_t* obl = (ushort_t*)(ws8 + 8388608);
  ushort_t* Boh = (ushort_t*)(ws8 + 16777216);
  ushort_t* Bol = (ushort_t*)(ws8 + 20971520);
  // region 1 (at +50.33 MB): x/w_qkv packs; later reused for qw/kw/vw
  char* r1 = ws8 + 50331648;
  ushort_t* Ah = (ushort_t*)r1;
  ushort_t* Al = (ushort_t*)(r1 + 8388608);
  ushort_t* Bqh = (ushort_t*)(r1 + 16777216);
  ushort_t* Bql = (ushort_t*)(r1 + 23068672);
  float* qw = (float*)r1;
  float* kwp = (float*)(r1 + 16777216);
  float* vwp = (float*)(r1 + 33554432);

  // 1) split/pack inputs to hi/lo bf16 (k-major)
  split_pack_rows<<<dim3(kN / 64, kC / 64), 256, 0, stream>>>(x, Ah, Al, kN,
                                                              kC);
  split_pack_w<<<dim3(3 * kC / 256, kC / 8), 256, 0, stream>>>(w_qkv, Bqh, Bql,
                                                               kC, 3 * kC);
  // 2) QKV projection (split-bf16 MFMA)
  gemm_mfma<<<dim3(3 * kC / 128, kN / 128), 256, 0, stream>>>(
      Ah, Al, Bqh, Bql, b_qkv, qkv, kN, 3 * kC, kC);
  // 3) RMS-norm + RoPE + window permute
  post_qkv<<<dim3(kN / 4), 256, 0, stream>>>(qkv, coords, qg, kg, qw, kwp,
                                             vwp);
  // 4) windowed attention (fp32), writes packed hi/lo bf16 output
  attn<<<dim3(8 * kH * 8), 256, 0, stream>>>(qw, kwp, vwp, obh, obl);
  // 5) pack w_out, output projection (split-bf16 MFMA)
  split_pack_w<<<dim3(kC / 256, kC / 8), 256, 0, stream>>>(w_out, Boh, Bol, kC,
                                                           kC);
  gemm_mfma<<<dim3(kC / 128, kN / 128), 256, 0, stream>>>(
      obh, obl, Boh, Bol, b_out, out, kN, kC, kC);
}

// Round 8
// 295.368 us; speedup vs baseline: 2.4572x; 1.4541x over previous
//
#include <hip/hip_runtime.h>
#include <math.h>

namespace {

typedef unsigned short ushort_t;
typedef __attribute__((ext_vector_type(8))) short bf16x8;
typedef __attribute__((ext_vector_type(8))) unsigned short u16x8;
typedef __attribute__((ext_vector_type(4))) unsigned short u16x4;
typedef __attribute__((ext_vector_type(4))) float f32x4;

constexpr int kN = 4096;   // tokens
constexpr int kC = 1024;   // channels
constexpr int kH = 16;     // heads
constexpr int kD = 64;     // head dim
constexpr int kL = 512;    // window length (8^3)

__device__ __forceinline__ ushort_t f2bf(float f) {
  unsigned u = __float_as_uint(f);
  unsigned r = (u + 0x7FFFu + ((u >> 16) & 1u)) >> 16;
  return (ushort_t)r;
}
__device__ __forceinline__ float bf2f(ushort_t h) {
  return __uint_as_float((unsigned)h << 16);
}

__device__ __forceinline__ void gload16(const void* g, void* l) {
  __builtin_amdgcn_global_load_lds(
      (const __attribute__((address_space(1))) unsigned int*)g,
      (__attribute__((address_space(3))) unsigned int*)l, 16, 0, 0);
}

// ---------------------------------------------------------------------------
// Split fp32 [M][K] row-major -> packed hi/lo bf16 [(K/8)][M][8] (k-major).
// ---------------------------------------------------------------------------
__global__ __launch_bounds__(256) void split_pack_rows(
    const float* __restrict__ src, ushort_t* __restrict__ hi,
    ushort_t* __restrict__ lo, int M, int K) {
  __shared__ __align__(16) ushort_t Th[64][72];
  __shared__ __align__(16) ushort_t Tl[64][72];
  const int t = threadIdx.x;
  const int m0 = blockIdx.x * 64, k0 = blockIdx.y * 64;
#pragma unroll
  for (int it = 0; it < 4; ++it) {
    const int slot = it * 256 + t;  // 0..1023
    const int m = slot >> 4;
    const int k4 = (slot & 15) * 4;
    const float4 v = *(const float4*)&src[(size_t)(m0 + m) * K + k0 + k4];
    float vv[4] = {v.x, v.y, v.z, v.w};
#pragma unroll
    for (int j = 0; j < 4; ++j) {
      const ushort_t hb = f2bf(vv[j]);
      Th[m][k4 + j] = hb;
      Tl[m][k4 + j] = f2bf(vv[j] - bf2f(hb));
    }
  }
  __syncthreads();
#pragma unroll
  for (int it = 0; it < 2; ++it) {
    const int slot = it * 256 + t;  // 0..511
    const int kcl = slot >> 6;      // 0..7
    const int m = slot & 63;
    const size_t o = ((size_t)(blockIdx.y * 8 + kcl) * M + m0 + m) * 8;
    *(u16x8*)&hi[o] = *(const u16x8*)&Th[m][kcl * 8];
    *(u16x8*)&lo[o] = *(const u16x8*)&Tl[m][kcl * 8];
  }
}

// ---------------------------------------------------------------------------
// Split fp32 [K][N] (k-major already) -> packed hi/lo bf16 [(K/8)][N][8].
// ---------------------------------------------------------------------------
__global__ __launch_bounds__(256) void split_pack_w(
    const float* __restrict__ src, ushort_t* __restrict__ hi,
    ushort_t* __restrict__ lo, int K, int N) {
  const int n = blockIdx.x * 256 + threadIdx.x;
  const int kcg = blockIdx.y;
  u16x8 h, l;
#pragma unroll
  for (int j = 0; j < 8; ++j) {
    const float v = src[(size_t)(kcg * 8 + j) * N + n];
    const ushort_t hb = f2bf(v);
    h[j] = hb;
    l[j] = f2bf(v - bf2f(hb));
  }
  const size_t o = ((size_t)kcg * N + n) * 8;
  *(u16x8*)&hi[o] = h;
  *(u16x8*)&lo[o] = l;
}

// ---------------------------------------------------------------------------
// Split-bf16 MFMA GEMM: C = Ah@Bh + Ah@Bl + Al@Bh + bias. (verified r4)
// ---------------------------------------------------------------------------
__global__ __launch_bounds__(256) void gemm_mfma(
    const ushort_t* __restrict__ Ah, const ushort_t* __restrict__ Al,
    const ushort_t* __restrict__ Bh, const ushort_t* __restrict__ Bl,
    const float* __restrict__ bias, float* __restrict__ C, int M, int N,
    int K) {
  __shared__ __align__(16) ushort_t As[2][4][128][8];  // [hl][kc][m][8]
  __shared__ __align__(16) ushort_t Bs[2][4][128][8];  // [hl][kc][n][8]

  const int t = threadIdx.x;
  const int lane = t & 63;
  const int wid = t >> 6;
  const int wr = wid >> 1, wc = wid & 1;
  const int l15 = lane & 15, lk = lane >> 4;
  const int row0 = blockIdx.y * 128, col0 = blockIdx.x * 128;

  f32x4 acc[4][4];
#pragma unroll
  for (int i = 0; i < 4; ++i)
#pragma unroll
    for (int j = 0; j < 4; ++j) acc[i][j] = (f32x4){0.f, 0.f, 0.f, 0.f};

  for (int k0 = 0; k0 < K; k0 += 32) {
    const int kq = k0 >> 3;
#pragma unroll
    for (int s = 0; s < 4; ++s) {
      const int li = s * 256 + t;
      const int kc = (li >> 7) & 3;
      const int r = li & 127;
      const size_t goff = ((size_t)(kq + kc));
      const ushort_t* Asrc = ((li >> 9) ? Al : Ah) + (goff * M + row0 + r) * 8;
      const ushort_t* Bsrc = ((li >> 9) ? Bl : Bh) + (goff * N + col0 + r) * 8;
      char* adst = (char*)(&As[0][0][0][0]) + (size_t)(s * 256 + wid * 64) * 16;
      char* bdst = (char*)(&Bs[0][0][0][0]) + (size_t)(s * 256 + wid * 64) * 16;
      gload16(Asrc, adst);
      gload16(Bsrc, bdst);
    }
    __syncthreads();

    bf16x8 af[2][4], bf[2][4];
#pragma unroll
    for (int hl = 0; hl < 2; ++hl)
#pragma unroll
      for (int f = 0; f < 4; ++f) {
        af[hl][f] = *(const bf16x8*)&As[hl][lk][wr * 64 + f * 16 + l15][0];
        bf[hl][f] = *(const bf16x8*)&Bs[hl][lk][wc * 64 + f * 16 + l15][0];
      }
#pragma unroll
    for (int mf = 0; mf < 4; ++mf)
#pragma unroll
      for (int nf = 0; nf < 4; ++nf) {
        acc[mf][nf] = __builtin_amdgcn_mfma_f32_16x16x32_bf16(
            af[0][mf], bf[0][nf], acc[mf][nf], 0, 0, 0);
        acc[mf][nf] = __builtin_amdgcn_mfma_f32_16x16x32_bf16(
            af[0][mf], bf[1][nf], acc[mf][nf], 0, 0, 0);
        acc[mf][nf] = __builtin_amdgcn_mfma_f32_16x16x32_bf16(
            af[1][mf], bf[0][nf], acc[mf][nf], 0, 0, 0);
      }
    __syncthreads();
  }

#pragma unroll
  for (int mf = 0; mf < 4; ++mf)
#pragma unroll
    for (int nf = 0; nf < 4; ++nf) {
      const int col = col0 + wc * 64 + nf * 16 + l15;
      const float bv = bias[col];
#pragma unroll
      for (int r = 0; r < 4; ++r) {
        const int row = row0 + wr * 64 + mf * 16 + lk * 4 + r;
        C[(size_t)row * N + col] = acc[mf][nf][r] + bv;
      }
    }
}

// ---------------------------------------------------------------------------
// Fused RMS-norm + RoPE + window permute. Emits MFMA-ready bf16:
//  qw,kw: [(D/8)=8][L=512][8] per (w,h); q pre-scaled by 1/8 (exact in bf16).
//  vw:    [(L/8)=64][D=64][8] per (w,h)  (k-major over window position).
// ---------------------------------------------------------------------------
__global__ __launch_bounds__(256) void post_qkv(
    const float* __restrict__ qkv, const int* __restrict__ coords,
    const float* __restrict__ qg, const float* __restrict__ kg,
    ushort_t* __restrict__ qwB, ushort_t* __restrict__ kwB,
    ushort_t* __restrict__ vwB) {
  const int token = blockIdx.x * 4 + (threadIdx.x >> 6);
  const int t = threadIdx.x & 63;
  const int h = t >> 2;
  const int quad = t & 3;
  const int d0 = quad * 16;

  const float* base = qkv + (size_t)token * (3 * kC) + h * kD + d0;
  float qv[16], kv[16], vv[16];
#pragma unroll
  for (int i = 0; i < 16; i += 4) {
    *(float4*)&qv[i] = *(const float4*)&base[i];
    *(float4*)&kv[i] = *(const float4*)&base[kC + i];
    *(float4*)&vv[i] = *(const float4*)&base[2 * kC + i];
  }

  float sq = 0.f, sk = 0.f;
#pragma unroll
  for (int i = 0; i < 16; ++i) {
    sq += qv[i] * qv[i];
    sk += kv[i] * kv[i];
  }
  sq += __shfl_xor(sq, 1);
  sq += __shfl_xor(sq, 2);
  sk += __shfl_xor(sk, 1);
  sk += __shfl_xor(sk, 2);
  const float qs = 8.0f / fmaxf(sqrtf(sq), 1e-12f);
  const float ks = 8.0f / fmaxf(sqrtf(sk), 1e-12f);

#pragma unroll
  for (int i = 0; i < 16; ++i) {
    qv[i] *= qs * qg[h * kD + d0 + i];
    kv[i] *= ks * kg[h * kD + d0 + i];
  }

  const int cz = coords[token * 4 + 1];
  const int cy = coords[token * 4 + 2];
  const int cx = coords[token * 4 + 3];

#pragma unroll
  for (int jj = 0; jj < 8; ++jj) {
    const int j = quad * 8 + jj;
    float ang = 0.f;
    if (j < 30) {
      const int axis = j / 10;
      const int f = j - axis * 10;
      const float coord = (float)(axis == 0 ? cz : (axis == 1 ? cy : cx));
      const float freq = expf(-(float)f * 0.92103403719761836f);
      ang = coord * freq;
    }
    float sn, cs;
    sincosf(ang, &sn, &cs);
    const float qre = qv[2 * jj], qim = qv[2 * jj + 1];
    qv[2 * jj + 0] = qre * cs - qim * sn;
    qv[2 * jj + 1] = qre * sn + qim * cs;
    const float kre = kv[2 * jj], kim = kv[2 * jj + 1];
    kv[2 * jj + 0] = kre * cs - kim * sn;
    kv[2 * jj + 1] = kre * sn + kim * cs;
  }

  const int w = ((cz >> 3) * 2 + (cy >> 3)) * 2 + (cx >> 3);
  const int p = ((cz & 7) * 8 + (cy & 7)) * 8 + (cx & 7);
  const int whq = w * kH + h;
  ushort_t* qo = qwB + (size_t)whq * 32768;
  ushort_t* ko = kwB + (size_t)whq * 32768;
  ushort_t* vo = vwB + (size_t)whq * 32768;

  u16x8 qh[2], kh[2];
#pragma unroll
  for (int c = 0; c < 2; ++c)
#pragma unroll
    for (int j = 0; j < 8; ++j) {
      qh[c][j] = f2bf(qv[c * 8 + j] * 0.125f);  // fold 1/sqrt(D), exact pow2
      kh[c][j] = f2bf(kv[c * 8 + j]);
    }
  const int kq0 = quad * 2;
  *(u16x8*)&qo[((kq0 + 0) * kL + p) * 8] = qh[0];
  *(u16x8*)&qo[((kq0 + 1) * kL + p) * 8] = qh[1];
  *(u16x8*)&ko[((kq0 + 0) * kL + p) * 8] = kh[0];
  *(u16x8*)&ko[((kq0 + 1) * kL + p) * 8] = kh[1];

  const int ck = p >> 3, jv = p & 7;
#pragma unroll
  for (int i = 0; i < 16; ++i)
    vo[(ck * 64 + d0 + i) * 8 + jv] = f2bf(vv[i]);
}

// ---------------------------------------------------------------------------
// Windowed attention via MFMA (bf16 inputs, f32 accum, online softmax).
// Block = (w, h, 128 q-rows); 4 waves, each owns 32 q-rows x 64 kv-cols/tile.
// K/V tiles staged by global_load_lds; Q frags in registers; P transposed
// through per-wave LDS (stride 72 u16 = 144B: 16B-aligned, spread banks).
// Epilogue writes O split hi/lo bf16 packed k-major for the out-projection.
// ---------------------------------------------------------------------------
__global__ __launch_bounds__(256) void attn_mfma(
    const ushort_t* __restrict__ qw, const ushort_t* __restrict__ kw,
    const ushort_t* __restrict__ vw, ushort_t* __restrict__ obh,
    ushort_t* __restrict__ obl) {
  __shared__ __align__(16) ushort_t Ks[8 * 64 * 8];  // [kq][c][8]
  __shared__ __align__(16) ushort_t Vs[8 * 64 * 8];  // [ck][d][8]
  __shared__ __align__(16) ushort_t Ps[4][32][72];   // per-wave P buffer

  const int bid = blockIdx.x;
  const int qt = bid & 3;
  const int h = (bid >> 2) & 15;
  const int w = bid >> 6;
  const int t = threadIdx.x;
  const int lane = t & 63;
  const int wid = t >> 6;
  const int l15 = lane & 15, lk = lane >> 4;
  const int whq = w * kH + h;
  const ushort_t* qbase = qw + (size_t)whq * 32768;
  const ushort_t* kbase = kw + (size_t)whq * 32768;
  const ushort_t* vbase = vw + (size_t)whq * 32768;

  const int qrow0 = qt * 128 + wid * 32;

  // Q A-frags held in registers for the whole kernel
  bf16x8 aq[2][2];
#pragma unroll
  for (int m = 0; m < 2; ++m)
#pragma unroll
    for (int ks = 0; ks < 2; ++ks)
      aq[m][ks] = *(const bf16x8*)&qbase[((ks * 4 + lk) * kL + qrow0 +
                                          m * 16 + l15) * 8];

  f32x4 oacc[2][4];
  float mrun[2][4], lrun[2][4];
#pragma unroll
  for (int m = 0; m < 2; ++m)
#pragma unroll
    for (int i = 0; i < 4; ++i) {
      mrun[m][i] = -1e30f;
      lrun[m][i] = 0.f;
    }
#pragma unroll
  for (int m = 0; m < 2; ++m)
#pragma unroll
    for (int nf = 0; nf < 4; ++nf) oacc[m][nf] = (f32x4){0.f, 0.f, 0.f, 0.f};

  for (int kt = 0; kt < 8; ++kt) {
    __syncthreads();  // previous tile fully consumed
    // stage K,V tiles: 1024+1024 chunks of 16B, 4 per thread
#pragma unroll
    for (int s = 0; s < 2; ++s) {
      const int idx = s * 256 + t;
      const int bidx = s * 256 + wid * 64;  // wave-uniform LDS chunk base
      gload16(&kbase[((idx >> 6) * kL + kt * 64 + (idx & 63)) * 8],
              (char*)Ks + (size_t)bidx * 16);
      gload16(&vbase[((kt * 8 + (idx >> 6)) * 64 + (idx & 63)) * 8],
              (char*)Vs + (size_t)bidx * 16);
    }
    __syncthreads();

    // S = Q K^T (scale pre-folded into Q)
    f32x4 sacc[2][4];
#pragma unroll
    for (int m = 0; m < 2; ++m)
#pragma unroll
      for (int nf = 0; nf < 4; ++nf) sacc[m][nf] = (f32x4){0.f, 0.f, 0.f, 0.f};
#pragma unroll
    for (int ks = 0; ks < 2; ++ks) {
      bf16x8 bk[4];
#pragma unroll
      for (int nf = 0; nf < 4; ++nf)
        bk[nf] = *(const bf16x8*)&Ks[((ks * 4 + lk) * 64 + nf * 16 + l15) * 8];
#pragma unroll
      for (int m = 0; m < 2; ++m)
#pragma unroll
        for (int nf = 0; nf < 4; ++nf)
          sacc[m][nf] = __builtin_amdgcn_mfma_f32_16x16x32_bf16(
              aq[m][ks], bk[nf], sacc[m][nf], 0, 0, 0);
    }

    // online softmax; P -> bf16 in per-wave LDS (transpose via LDS)
#pragma unroll
    for (int m = 0; m < 2; ++m)
#pragma unroll
      for (int i = 0; i < 4; ++i) {
        float rmax = fmaxf(fmaxf(sacc[m][0][i], sacc[m][1][i]),
                           fmaxf(sacc[m][2][i], sacc[m][3][i]));
        rmax = fmaxf(rmax, __shfl_xor(rmax, 1));
        rmax = fmaxf(rmax, __shfl_xor(rmax, 2));
        rmax = fmaxf(rmax, __shfl_xor(rmax, 4));
        rmax = fmaxf(rmax, __shfl_xor(rmax, 8));
        const float mn = fmaxf(mrun[m][i], rmax);
        const float corr = __expf(mrun[m][i] - mn);
        mrun[m][i] = mn;
        float p[4];
        float rs = 0.f;
#pragma unroll
        for (int nf = 0; nf < 4; ++nf) {
          p[nf] = __expf(sacc[m][nf][i] - mn);
          rs += p[nf];
        }
        rs += __shfl_xor(rs, 1);
        rs += __shfl_xor(rs, 2);
        rs += __shfl_xor(rs, 4);
        rs += __shfl_xor(rs, 8);
        lrun[m][i] = lrun[m][i] * corr + rs;
#pragma unroll
        for (int nf = 0; nf < 4; ++nf) oacc[m][nf][i] *= corr;
        const int row = m * 16 + lk * 4 + i;
#pragma unroll
        for (int nf = 0; nf < 4; ++nf)
          Ps[wid][row][nf * 16 + l15] = f2bf(p[nf]);
      }

    // O += P V  (wave-private Ps: no block barrier needed)
#pragma unroll
    for (int ks = 0; ks < 2; ++ks) {
      bf16x8 pa[2], bv[4];
#pragma unroll
      for (int m = 0; m < 2; ++m)
        pa[m] = *(const bf16x8*)&Ps[wid][m * 16 + l15][ks * 32 + lk * 8];
#pragma unroll
      for (int nf = 0; nf < 4; ++nf)
        bv[nf] = *(const bf16x8*)&Vs[((ks * 4 + lk) * 64 + nf * 16 + l15) * 8];
#pragma unroll
      for (int m = 0; m < 2; ++m)
#pragma unroll
        for (int nf = 0; nf < 4; ++nf)
          oacc[m][nf] = __builtin_amdgcn_mfma_f32_16x16x32_bf16(
              pa[m], bv[nf], oacc[m][nf], 0, 0, 0);
    }
  }

  // epilogue: /l, split hi/lo, scatter to token order (packed k-major)
  const int wz = w >> 2, wy = (w >> 1) & 1, wx = w & 1;
#pragma unroll
  for (int m = 0; m < 2; ++m)
#pragma unroll
    for (int i = 0; i < 4; ++i) {
      const int pg = qrow0 + m * 16 + lk * 4 + i;
      const int pz = pg >> 6, py = (pg >> 3) & 7, px = pg & 7;
      const int n = ((wz * 8 + pz) * 16 + wy * 8 + py) * 16 + wx * 8 + px;
      const float inv = 1.0f / lrun[m][i];
#pragma unroll
      for (int nf = 0; nf < 4; ++nf) {
        const int c0 = h * kD + nf * 16 + l15;
        const float v = oacc[m][nf][i] * inv;
        const ushort_t hb = f2bf(v);
        const size_t o = ((size_t)(c0 >> 3) * kN + n) * 8 + (c0 & 7);
        obh[o] = hb;
        obl[o] = f2bf(v - bf2f(hb));
      }
    }
}

}  // namespace

extern "C" void kernel_launch(void* const* d_in, const int* in_sizes, int n_in,
                              void* d_out, int out_size, void* d_ws,
                              size_t ws_size, hipStream_t stream) {
  const float* x = (const float*)d_in[0];
  const int* coords = (const int*)d_in[1];
  const float* w_qkv = (const float*)d_in[2];
  const float* b_qkv = (const float*)d_in[3];
  const float* qg = (const float*)d_in[4];
  const float* kg = (const float*)d_in[5];
  const float* w_out = (const float*)d_in[6];
  const float* b_out = (const float*)d_in[7];
  float* out = (float*)d_out;

  char* ws8 = (char*)d_ws;
  // region 0: qkv fp32 (48 MB); later reused for obuf hi/lo + w_out pack
  float* qkv = (float*)ws8;
  ushort_t* obh = (ushort_t*)ws8;
  ushort_t* obl = (ushort_t*)(ws8 + 8388608);
  ushort_t* Boh = (ushort_t*)(ws8 + 16777216);
  ushort_t* Bol = (ushort_t*)(ws8 + 20971520);
  // region 1 (at +50.33 MB): x/w_qkv packs; later reused for bf16 q/k/v
  char* r1 = ws8 + 50331648;
  ushort_t* Ah = (ushort_t*)r1;
  ushort_t* Al = (ushort_t*)(r1 + 8388608);
  ushort_t* Bqh = (ushort_t*)(r1 + 16777216);
  ushort_t* Bql = (ushort_t*)(r1 + 23068672);
  ushort_t* qwB = (ushort_t*)r1;
  ushort_t* kwB = (ushort_t*)(r1 + 8388608);
  ushort_t* vwB = (ushort_t*)(r1 + 16777216);

  // 1) split/pack inputs to hi/lo bf16 (k-major)
  split_pack_rows<<<dim3(kN / 64, kC / 64), 256, 0, stream>>>(x, Ah, Al, kN,
                                                              kC);
  split_pack_w<<<dim3(3 * kC / 256, kC / 8), 256, 0, stream>>>(w_qkv, Bqh, Bql,
                                                               kC, 3 * kC);
  // 2) QKV projection (split-bf16 MFMA)
  gemm_mfma<<<dim3(3 * kC / 128, kN / 128), 256, 0, stream>>>(
      Ah, Al, Bqh, Bql, b_qkv, qkv, kN, 3 * kC, kC);
  // 3) RMS-norm + RoPE + window permute -> MFMA-ready bf16 q/k/v
  //    (overwrites Ah/Al/Bqh regions, which are dead after step 2)
  post_qkv<<<dim3(kN / 4), 256, 0, stream>>>(qkv, coords, qg, kg, qwB, kwB,
                                             vwB);
  // 4) windowed attention (bf16 MFMA), writes packed hi/lo bf16 output
  attn_mfma<<<dim3(4 * kH * 8), 256, 0, stream>>>(qwB, kwB, vwB, obh, obl);
  // 5) pack w_out, output projection (split-bf16 MFMA)
  split_pack_w<<<dim3(kC / 256, kC / 8), 256, 0, stream>>>(w_out, Boh, Bol, kC,
                                                           kC);
  gemm_mfma<<<dim3(kC / 128, kN / 128), 256, 0, stream>>>(
      obh, obl, Boh, Bol, b_out, out, kN, kC, kC);
}

// Round 10
// 220.256 us; speedup vs baseline: 3.2952x; 1.3410x over previous
//
#include <hip/hip_runtime.h>
#include <math.h>

namespace {

typedef _Float16 f16_t;
typedef __attribute__((ext_vector_type(8))) _Float16 f16x8;
typedef __attribute__((ext_vector_type(4))) float f32x4;

constexpr int kN = 4096;   // tokens
constexpr int kC = 1024;   // channels
constexpr int kH = 16;     // heads
constexpr int kD = 64;     // head dim
constexpr int kL = 512;    // window length (8^3)

__device__ __forceinline__ void gload16(const void* g, void* l) {
  __builtin_amdgcn_global_load_lds(
      (const __attribute__((address_space(1))) unsigned int*)g,
      (__attribute__((address_space(3))) unsigned int*)l, 16, 0, 0);
}

// ---------------------------------------------------------------------------
// fp32 [M][K] row-major -> fp16 [(K/8)][M][8] (k-major packed).
// 64x64 tile via LDS transpose; coalesced reads and writes.
// ---------------------------------------------------------------------------
__global__ __launch_bounds__(256) void pack_rows_f16(
    const float* __restrict__ src, f16_t* __restrict__ dst, int M, int K) {
  __shared__ __align__(16) f16_t Th[64][72];
  const int t = threadIdx.x;
  const int m0 = blockIdx.x * 64, k0 = blockIdx.y * 64;
#pragma unroll
  for (int it = 0; it < 4; ++it) {
    const int slot = it * 256 + t;  // 0..1023
    const int m = slot >> 4;
    const int k4 = (slot & 15) * 4;
    const float4 v = *(const float4*)&src[(size_t)(m0 + m) * K + k0 + k4];
    Th[m][k4 + 0] = (f16_t)v.x;
    Th[m][k4 + 1] = (f16_t)v.y;
    Th[m][k4 + 2] = (f16_t)v.z;
    Th[m][k4 + 3] = (f16_t)v.w;
  }
  __syncthreads();
#pragma unroll
  for (int it = 0; it < 2; ++it) {
    const int slot = it * 256 + t;  // 0..511
    const int kcl = slot >> 6;      // 0..7
    const int m = slot & 63;
    const size_t o = ((size_t)(blockIdx.y * 8 + kcl) * M + m0 + m) * 8;
    *(f16x8*)&dst[o] = *(const f16x8*)&Th[m][kcl * 8];
  }
}

// ---------------------------------------------------------------------------
// fp32 [K][N] (k-major already) -> fp16 [(K/8)][N][8]. grid (N/256, K/8).
// ---------------------------------------------------------------------------
__global__ __launch_bounds__(256) void pack_w_f16(
    const float* __restrict__ src, f16_t* __restrict__ dst, int K, int N) {
  const int n = blockIdx.x * 256 + threadIdx.x;
  const int kcg = blockIdx.y;
  f16x8 h;
#pragma unroll
  for (int j = 0; j < 8; ++j)
    h[j] = (f16_t)src[(size_t)(kcg * 8 + j) * N + n];
  *(f16x8*)&dst[((size_t)kcg * N + n) * 8] = h;
}

// ---------------------------------------------------------------------------
// Single-pass fp16 MFMA GEMM: C[M][N] = A@B + bias.
// A,B packed k-major [(K/8)][rows-or-cols][8] fp16. 128x128 tile, BK=32,
// 4 waves (2x2), each wave 64x64 via 4x4 frags of mfma_f32_16x16x32_f16.
// Same staging/LDS skeleton as the r4/r8-verified split-bf16 gemm; LDS
// halves to 16KB (A 8KB + B 8KB) -> higher occupancy.
// ---------------------------------------------------------------------------
__global__ __launch_bounds__(256) void gemm_f16(
    const f16_t* __restrict__ A, const f16_t* __restrict__ B,
    const float* __restrict__ bias, float* __restrict__ C, int M, int N,
    int K) {
  __shared__ __align__(16) f16_t As[4][128][8];  // [kc][m][8]
  __shared__ __align__(16) f16_t Bs[4][128][8];  // [kc][n][8]

  const int t = threadIdx.x;
  const int lane = t & 63;
  const int wid = t >> 6;
  const int wr = wid >> 1, wc = wid & 1;
  const int l15 = lane & 15, lk = lane >> 4;
  const int row0 = blockIdx.y * 128, col0 = blockIdx.x * 128;

  f32x4 acc[4][4];
#pragma unroll
  for (int i = 0; i < 4; ++i)
#pragma unroll
    for (int j = 0; j < 4; ++j) acc[i][j] = (f32x4){0.f, 0.f, 0.f, 0.f};

  for (int k0 = 0; k0 < K; k0 += 32) {
    const int kq = k0 >> 3;
    // stage 16 KB: 512 chunks A + 512 chunks B, 4 x 16B per thread
#pragma unroll
    for (int s = 0; s < 2; ++s) {
      const int li = s * 256 + t;  // 0..511
      const int kc = li >> 7;
      const int r = li & 127;
      const size_t goff = (size_t)(kq + kc);
      char* adst = (char*)(&As[0][0][0]) + (size_t)(s * 256 + wid * 64) * 16;
      char* bdst = (char*)(&Bs[0][0][0]) + (size_t)(s * 256 + wid * 64) * 16;
      gload16(&A[(goff * M + row0 + r) * 8], adst);
      gload16(&B[(goff * N + col0 + r) * 8], bdst);
    }
    __syncthreads();

    f16x8 af[4], bf[4];
#pragma unroll
    for (int f = 0; f < 4; ++f) {
      af[f] = *(const f16x8*)&As[lk][wr * 64 + f * 16 + l15][0];
      bf[f] = *(const f16x8*)&Bs[lk][wc * 64 + f * 16 + l15][0];
    }
#pragma unroll
    for (int mf = 0; mf < 4; ++mf)
#pragma unroll
      for (int nf = 0; nf < 4; ++nf)
        acc[mf][nf] = __builtin_amdgcn_mfma_f32_16x16x32_f16(
            af[mf], bf[nf], acc[mf][nf], 0, 0, 0);
    __syncthreads();
  }

#pragma unroll
  for (int mf = 0; mf < 4; ++mf)
#pragma unroll
    for (int nf = 0; nf < 4; ++nf) {
      const int col = col0 + wc * 64 + nf * 16 + l15;
      const float bv = bias[col];
#pragma unroll
      for (int r = 0; r < 4; ++r) {
        const int row = row0 + wr * 64 + mf * 16 + lk * 4 + r;
        C[(size_t)row * N + col] = acc[mf][nf][r] + bv;
      }
    }
}

// ---------------------------------------------------------------------------
// Fused RMS-norm + RoPE + window permute. Emits MFMA-ready fp16:
//  qw,kw: [(D/8)=8][L=512][8] per (w,h); q pre-scaled by 1/8 (exact pow2).
//  vw:    [(L/8)=64][D=64][8] per (w,h)  (k-major over window position).
// ---------------------------------------------------------------------------
__global__ __launch_bounds__(256) void post_qkv(
    const float* __restrict__ qkv, const int* __restrict__ coords,
    const float* __restrict__ qg, const float* __restrict__ kg,
    f16_t* __restrict__ qwF, f16_t* __restrict__ kwF,
    f16_t* __restrict__ vwF) {
  const int token = blockIdx.x * 4 + (threadIdx.x >> 6);
  const int t = threadIdx.x & 63;
  const int h = t >> 2;
  const int quad = t & 3;
  const int d0 = quad * 16;

  const float* base = qkv + (size_t)token * (3 * kC) + h * kD + d0;
  float qv[16], kv[16], vv[16];
#pragma unroll
  for (int i = 0; i < 16; i += 4) {
    *(float4*)&qv[i] = *(const float4*)&base[i];
    *(float4*)&kv[i] = *(const float4*)&base[kC + i];
    *(float4*)&vv[i] = *(const float4*)&base[2 * kC + i];
  }

  float sq = 0.f, sk = 0.f;
#pragma unroll
  for (int i = 0; i < 16; ++i) {
    sq += qv[i] * qv[i];
    sk += kv[i] * kv[i];
  }
  sq += __shfl_xor(sq, 1);
  sq += __shfl_xor(sq, 2);
  sk += __shfl_xor(sk, 1);
  sk += __shfl_xor(sk, 2);
  const float qs = 8.0f / fmaxf(sqrtf(sq), 1e-12f);
  const float ks = 8.0f / fmaxf(sqrtf(sk), 1e-12f);

#pragma unroll
  for (int i = 0; i < 16; ++i) {
    qv[i] *= qs * qg[h * kD + d0 + i];
    kv[i] *= ks * kg[h * kD + d0 + i];
  }

  const int cz = coords[token * 4 + 1];
  const int cy = coords[token * 4 + 2];
  const int cx = coords[token * 4 + 3];

#pragma unroll
  for (int jj = 0; jj < 8; ++jj) {
    const int j = quad * 8 + jj;
    float ang = 0.f;
    if (j < 30) {
      const int axis = j / 10;
      const int f = j - axis * 10;
      const float coord = (float)(axis == 0 ? cz : (axis == 1 ? cy : cx));
      const float freq = expf(-(float)f * 0.92103403719761836f);
      ang = coord * freq;
    }
    float sn, cs;
    sincosf(ang, &sn, &cs);
    const float qre = qv[2 * jj], qim = qv[2 * jj + 1];
    qv[2 * jj + 0] = qre * cs - qim * sn;
    qv[2 * jj + 1] = qre * sn + qim * cs;
    const float kre = kv[2 * jj], kim = kv[2 * jj + 1];
    kv[2 * jj + 0] = kre * cs - kim * sn;
    kv[2 * jj + 1] = kre * sn + kim * cs;
  }

  const int w = ((cz >> 3) * 2 + (cy >> 3)) * 2 + (cx >> 3);
  const int p = ((cz & 7) * 8 + (cy & 7)) * 8 + (cx & 7);
  const int whq = w * kH + h;
  f16_t* qo = qwF + (size_t)whq * 32768;
  f16_t* ko = kwF + (size_t)whq * 32768;
  f16_t* vo = vwF + (size_t)whq * 32768;

  f16x8 qh[2], kh[2];
#pragma unroll
  for (int c = 0; c < 2; ++c)
#pragma unroll
    for (int j = 0; j < 8; ++j) {
      qh[c][j] = (f16_t)(qv[c * 8 + j] * 0.125f);  // fold 1/sqrt(D)
      kh[c][j] = (f16_t)kv[c * 8 + j];
    }
  const int kq0 = quad * 2;
  *(f16x8*)&qo[((kq0 + 0) * kL + p) * 8] = qh[0];
  *(f16x8*)&qo[((kq0 + 1) * kL + p) * 8] = qh[1];
  *(f16x8*)&ko[((kq0 + 0) * kL + p) * 8] = kh[0];
  *(f16x8*)&ko[((kq0 + 1) * kL + p) * 8] = kh[1];

  const int ck = p >> 3, jv = p & 7;
#pragma unroll
  for (int i = 0; i < 16; ++i)
    vo[(ck * 64 + d0 + i) * 8 + jv] = (f16_t)vv[i];
}

// ---------------------------------------------------------------------------
// Windowed attention via fp16 MFMA (f32 accum, online softmax).
// Block = (w, h, 128 q-rows); 4 waves, each owns 32 q-rows x 64 kv-cols/tile.
// K/V staged via global_load_lds; Q frags in registers; P through per-wave
// LDS (stride 72 f16 = 144B). Epilogue writes O fp16 packed k-major.
// ---------------------------------------------------------------------------
__global__ __launch_bounds__(256) void attn_mfma(
    const f16_t* __restrict__ qw, const f16_t* __restrict__ kw,
    const f16_t* __restrict__ vw, f16_t* __restrict__ ob) {
  __shared__ __align__(16) f16_t Ks[8 * 64 * 8];  // [kq][c][8]
  __shared__ __align__(16) f16_t Vs[8 * 64 * 8];  // [ck][d][8]
  __shared__ __align__(16) f16_t Ps[4][32][72];   // per-wave P buffer

  const int bid = blockIdx.x;
  const int qt = bid & 3;
  const int h = (bid >> 2) & 15;
  const int w = bid >> 6;
  const int t = threadIdx.x;
  const int lane = t & 63;
  const int wid = t >> 6;
  const int l15 = lane & 15, lk = lane >> 4;
  const int whq = w * kH + h;
  const f16_t* qbase = qw + (size_t)whq * 32768;
  const f16_t* kbase = kw + (size_t)whq * 32768;
  const f16_t* vbase = vw + (size_t)whq * 32768;

  const int qrow0 = qt * 128 + wid * 32;

  f16x8 aq[2][2];
#pragma unroll
  for (int m = 0; m < 2; ++m)
#pragma unroll
    for (int ks = 0; ks < 2; ++ks)
      aq[m][ks] = *(const f16x8*)&qbase[((ks * 4 + lk) * kL + qrow0 +
                                         m * 16 + l15) * 8];

  f32x4 oacc[2][4];
  float mrun[2][4], lrun[2][4];
#pragma unroll
  for (int m = 0; m < 2; ++m)
#pragma unroll
    for (int i = 0; i < 4; ++i) {
      mrun[m][i] = -1e30f;
      lrun[m][i] = 0.f;
    }
#pragma unroll
  for (int m = 0; m < 2; ++m)
#pragma unroll
    for (int nf = 0; nf < 4; ++nf) oacc[m][nf] = (f32x4){0.f, 0.f, 0.f, 0.f};

  for (int kt = 0; kt < 8; ++kt) {
    __syncthreads();
#pragma unroll
    for (int s = 0; s < 2; ++s) {
      const int idx = s * 256 + t;
      const int bidx = s * 256 + wid * 64;
      gload16(&kbase[((idx >> 6) * kL + kt * 64 + (idx & 63)) * 8],
              (char*)Ks + (size_t)bidx * 16);
      gload16(&vbase[((kt * 8 + (idx >> 6)) * 64 + (idx & 63)) * 8],
              (char*)Vs + (size_t)bidx * 16);
    }
    __syncthreads();

    // S = Q K^T (scale pre-folded into Q)
    f32x4 sacc[2][4];
#pragma unroll
    for (int m = 0; m < 2; ++m)
#pragma unroll
      for (int nf = 0; nf < 4; ++nf) sacc[m][nf] = (f32x4){0.f, 0.f, 0.f, 0.f};
#pragma unroll
    for (int ks = 0; ks < 2; ++ks) {
      f16x8 bk[4];
#pragma unroll
      for (int nf = 0; nf < 4; ++nf)
        bk[nf] = *(const f16x8*)&Ks[((ks * 4 + lk) * 64 + nf * 16 + l15) * 8];
#pragma unroll
      for (int m = 0; m < 2; ++m)
#pragma unroll
        for (int nf = 0; nf < 4; ++nf)
          sacc[m][nf] = __builtin_amdgcn_mfma_f32_16x16x32_f16(
              aq[m][ks], bk[nf], sacc[m][nf], 0, 0, 0);
    }

    // online softmax; P -> fp16 in per-wave LDS (transpose via LDS)
#pragma unroll
    for (int m = 0; m < 2; ++m)
#pragma unroll
      for (int i = 0; i < 4; ++i) {
        float rmax = fmaxf(fmaxf(sacc[m][0][i], sacc[m][1][i]),
                           fmaxf(sacc[m][2][i], sacc[m][3][i]));
        rmax = fmaxf(rmax, __shfl_xor(rmax, 1));
        rmax = fmaxf(rmax, __shfl_xor(rmax, 2));
        rmax = fmaxf(rmax, __shfl_xor(rmax, 4));
        rmax = fmaxf(rmax, __shfl_xor(rmax, 8));
        const float mn = fmaxf(mrun[m][i], rmax);
        const float corr = __expf(mrun[m][i] - mn);
        mrun[m][i] = mn;
        float p[4];
        float rs = 0.f;
#pragma unroll
        for (int nf = 0; nf < 4; ++nf) {
          p[nf] = __expf(sacc[m][nf][i] - mn);
          rs += p[nf];
        }
        rs += __shfl_xor(rs, 1);
        rs += __shfl_xor(rs, 2);
        rs += __shfl_xor(rs, 4);
        rs += __shfl_xor(rs, 8);
        lrun[m][i] = lrun[m][i] * corr + rs;
#pragma unroll
        for (int nf = 0; nf < 4; ++nf) oacc[m][nf][i] *= corr;
        const int row = m * 16 + lk * 4 + i;
#pragma unroll
        for (int nf = 0; nf < 4; ++nf)
          Ps[wid][row][nf * 16 + l15] = (f16_t)p[nf];
      }

    // O += P V  (wave-private Ps: no block barrier needed)
#pragma unroll
    for (int ks = 0; ks < 2; ++ks) {
      f16x8 pa[2], bv[4];
#pragma unroll
      for (int m = 0; m < 2; ++m)
        pa[m] = *(const f16x8*)&Ps[wid][m * 16 + l15][ks * 32 + lk * 8];
#pragma unroll
      for (int nf = 0; nf < 4; ++nf)
        bv[nf] = *(const f16x8*)&Vs[((ks * 4 + lk) * 64 + nf * 16 + l15) * 8];
#pragma unroll
      for (int m = 0; m < 2; ++m)
#pragma unroll
        for (int nf = 0; nf < 4; ++nf)
          oacc[m][nf] = __builtin_amdgcn_mfma_f32_16x16x32_f16(
              pa[m], bv[nf], oacc[m][nf], 0, 0, 0);
    }
  }

  // epilogue: /l, fp16, scatter to token order (packed k-major)
  const int wz = w >> 2, wy = (w >> 1) & 1, wx = w & 1;
#pragma unroll
  for (int m = 0; m < 2; ++m)
#pragma unroll
    for (int i = 0; i < 4; ++i) {
      const int pg = qrow0 + m * 16 + lk * 4 + i;
      const int pz = pg >> 6, py = (pg >> 3) & 7, px = pg & 7;
      const int n = ((wz * 8 + pz) * 16 + wy * 8 + py) * 16 + wx * 8 + px;
      const float inv = 1.0f / lrun[m][i];
#pragma unroll
      for (int nf = 0; nf < 4; ++nf) {
        const int c0 = h * kD + nf * 16 + l15;
        ob[((size_t)(c0 >> 3) * kN + n) * 8 + (c0 & 7)] =
            (f16_t)(oacc[m][nf][i] * inv);
      }
    }
}

}  // namespace

extern "C" void kernel_launch(void* const* d_in, const int* in_sizes, int n_in,
                              void* d_out, int out_size, void* d_ws,
                              size_t ws_size, hipStream_t stream) {
  const float* x = (const float*)d_in[0];
  const int* coords = (const int*)d_in[1];
  const float* w_qkv = (const float*)d_in[2];
  const float* b_qkv = (const float*)d_in[3];
  const float* qg = (const float*)d_in[4];
  const float* kg = (const float*)d_in[5];
  const float* w_out = (const float*)d_in[6];
  const float* b_out = (const float*)d_in[7];
  float* out = (float*)d_out;

  char* ws8 = (char*)d_ws;
  // region 0 (0..48MB): qkv fp32; after post_qkv reused for obF + BoF
  float* qkv = (float*)ws8;
  f16_t* obF = (f16_t*)ws8;                       // 8 MB
  f16_t* BoF = (f16_t*)(ws8 + 8388608);           // 2 MB
  // region 1 (at +48MB): x/w_qkv fp16 packs; after QKV gemm reused q/k/v
  char* r1 = ws8 + 50331648;
  f16_t* AF = (f16_t*)r1;                         // 8 MB
  f16_t* BqF = (f16_t*)(r1 + 8388608);            // 6 MB
  f16_t* qwF = (f16_t*)r1;                        // 8 MB
  f16_t* kwF = (f16_t*)(r1 + 8388608);            // 8 MB
  f16_t* vwF = (f16_t*)(r1 + 16777216);           // 8 MB

  // 1) pack inputs to fp16 (k-major)
  pack_rows_f16<<<dim3(kN / 64, kC / 64), 256, 0, stream>>>(x, AF, kN, kC);
  pack_w_f16<<<dim3(3 * kC / 256, kC / 8), 256, 0, stream>>>(w_qkv, BqF, kC,
                                                             3 * kC);
  // 2) QKV projection (single-pass fp16 MFMA)
  gemm_f16<<<dim3(3 * kC / 128, kN / 128), 256, 0, stream>>>(
      AF, BqF, b_qkv, qkv, kN, 3 * kC, kC);
  // 3) RMS-norm + RoPE + window permute -> fp16 q/k/v (overwrites AF/BqF)
  post_qkv<<<dim3(kN / 4), 256, 0, stream>>>(qkv, coords, qg, kg, qwF, kwF,
                                             vwF);
  // 4) windowed attention (fp16 MFMA), writes fp16 packed O (overwrites qkv)
  attn_mfma<<<dim3(4 * kH * 8), 256, 0, stream>>>(qwF, kwF, vwF, obF);
  // 5) pack w_out, output projection (single-pass fp16 MFMA)
  pack_w_f16<<<dim3(kC / 256, kC / 8), 256, 0, stream>>>(w_out, BoF, kC, kC);
  gemm_f16<<<dim3(kC / 128, kN / 128), 256, 0, stream>>>(
      obF, BoF, b_out, out, kN, kC, kC);
}

// Round 11
// 199.629 us; speedup vs baseline: 3.6357x; 1.1033x over previous
//
#include <hip/hip_runtime.h>
#include <math.h>

namespace {

typedef _Float16 f16_t;
typedef __attribute__((ext_vector_type(8))) _Float16 f16x8;
typedef __attribute__((ext_vector_type(4))) float f32x4;

constexpr int kN = 4096;   // tokens
constexpr int kC = 1024;   // channels
constexpr int kH = 16;     // heads
constexpr int kD = 64;     // head dim
constexpr int kL = 512;    // window length (8^3)

__device__ __forceinline__ void gload16(const void* g, void* l) {
  __builtin_amdgcn_global_load_lds(
      (const __attribute__((address_space(1))) unsigned int*)g,
      (__attribute__((address_space(3))) unsigned int*)l, 16, 0, 0);
}

// ---------------------------------------------------------------------------
// fp32 [M][K] row-major -> fp16 [(K/8)][M][8] (k-major packed).
// ---------------------------------------------------------------------------
__global__ __launch_bounds__(256) void pack_rows_f16(
    const float* __restrict__ src, f16_t* __restrict__ dst, int M, int K) {
  __shared__ __align__(16) f16_t Th[64][72];
  const int t = threadIdx.x;
  const int m0 = blockIdx.x * 64, k0 = blockIdx.y * 64;
#pragma unroll
  for (int it = 0; it < 4; ++it) {
    const int slot = it * 256 + t;  // 0..1023
    const int m = slot >> 4;
    const int k4 = (slot & 15) * 4;
    const float4 v = *(const float4*)&src[(size_t)(m0 + m) * K + k0 + k4];
    Th[m][k4 + 0] = (f16_t)v.x;
    Th[m][k4 + 1] = (f16_t)v.y;
    Th[m][k4 + 2] = (f16_t)v.z;
    Th[m][k4 + 3] = (f16_t)v.w;
  }
  __syncthreads();
#pragma unroll
  for (int it = 0; it < 2; ++it) {
    const int slot = it * 256 + t;  // 0..511
    const int kcl = slot >> 6;      // 0..7
    const int m = slot & 63;
    const size_t o = ((size_t)(blockIdx.y * 8 + kcl) * M + m0 + m) * 8;
    *(f16x8*)&dst[o] = *(const f16x8*)&Th[m][kcl * 8];
  }
}

// ---------------------------------------------------------------------------
// fp32 [K][N] (k-major already) -> fp16 [(K/8)][N][8]. grid (N/256, K/8).
// ---------------------------------------------------------------------------
__global__ __launch_bounds__(256) void pack_w_f16(
    const float* __restrict__ src, f16_t* __restrict__ dst, int K, int N) {
  const int n = blockIdx.x * 256 + threadIdx.x;
  const int kcg = blockIdx.y;
  f16x8 h;
#pragma unroll
  for (int j = 0; j < 8; ++j)
    h[j] = (f16_t)src[(size_t)(kcg * 8 + j) * N + n];
  *(f16x8*)&dst[((size_t)kcg * N + n) * 8] = h;
}

// ---------------------------------------------------------------------------
// Generic single-pass fp16 MFMA GEMM with fp32 out + bias (out-projection).
// Verified r10. 128x128 tile, BK=32, 4 waves (2x2), 4x4 frags 16x16x32.
// ---------------------------------------------------------------------------
__global__ __launch_bounds__(256) void gemm_f16(
    const f16_t* __restrict__ A, const f16_t* __restrict__ B,
    const float* __restrict__ bias, float* __restrict__ C, int M, int N,
    int K) {
  __shared__ __align__(16) f16_t As[4][128][8];  // [kc][m][8]
  __shared__ __align__(16) f16_t Bs[4][128][8];  // [kc][n][8]

  const int t = threadIdx.x;
  const int lane = t & 63;
  const int wid = t >> 6;
  const int wr = wid >> 1, wc = wid & 1;
  const int l15 = lane & 15, lk = lane >> 4;
  const int row0 = blockIdx.y * 128, col0 = blockIdx.x * 128;

  f32x4 acc[4][4];
#pragma unroll
  for (int i = 0; i < 4; ++i)
#pragma unroll
    for (int j = 0; j < 4; ++j) acc[i][j] = (f32x4){0.f, 0.f, 0.f, 0.f};

  for (int k0 = 0; k0 < K; k0 += 32) {
    const int kq = k0 >> 3;
#pragma unroll
    for (int s = 0; s < 2; ++s) {
      const int li = s * 256 + t;  // 0..511
      const int kc = li >> 7;
      const int r = li & 127;
      const size_t goff = (size_t)(kq + kc);
      char* adst = (char*)(&As[0][0][0]) + (size_t)(s * 256 + wid * 64) * 16;
      char* bdst = (char*)(&Bs[0][0][0]) + (size_t)(s * 256 + wid * 64) * 16;
      gload16(&A[(goff * M + row0 + r) * 8], adst);
      gload16(&B[(goff * N + col0 + r) * 8], bdst);
    }
    __syncthreads();

    f16x8 af[4], bf[4];
#pragma unroll
    for (int f = 0; f < 4; ++f) {
      af[f] = *(const f16x8*)&As[lk][wr * 64 + f * 16 + l15][0];
      bf[f] = *(const f16x8*)&Bs[lk][wc * 64 + f * 16 + l15][0];
    }
#pragma unroll
    for (int mf = 0; mf < 4; ++mf)
#pragma unroll
      for (int nf = 0; nf < 4; ++nf)
        acc[mf][nf] = __builtin_amdgcn_mfma_f32_16x16x32_f16(
            af[mf], bf[nf], acc[mf][nf], 0, 0, 0);
    __syncthreads();
  }

#pragma unroll
  for (int mf = 0; mf < 4; ++mf)
#pragma unroll
    for (int nf = 0; nf < 4; ++nf) {
      const int col = col0 + wc * 64 + nf * 16 + l15;
      const float bv = bias[col];
#pragma unroll
      for (int r = 0; r < 4; ++r) {
        const int row = row0 + wr * 64 + mf * 16 + lk * 4 + r;
        C[(size_t)row * N + col] = acc[mf][nf][r] + bv;
      }
    }
}

// ---------------------------------------------------------------------------
// QKV GEMM with FUSED epilogue: bias + per-head RMS-norm + RoPE + window
// permute + fp16 pack, written directly in the attention layouts:
//  q,k: [(D/8)=8][L=512][8] per (w,h); q pre-scaled by 1/8.
//  v:   [(L/8)=64][D=64][8] per (w,h).
// Wave sub-tile = 64 rows (tokens) x 64 cols = exactly one head of q|k|v
// (tsel/h wave-uniform). C/D frag layout: row=mf*16+lk*4+r, col=nf*16+l15.
// Norm: square-sum over nf + shfl_xor(1,2,4,8) within 16-lane group.
// RoPE: pair partner differs in lane bit0 -> shfl_xor(v,1).
// ---------------------------------------------------------------------------
__global__ __launch_bounds__(256) void gemm_qkv(
    const f16_t* __restrict__ A, const f16_t* __restrict__ B,
    const float* __restrict__ bias, const int* __restrict__ coords,
    const float* __restrict__ qg, const float* __restrict__ kg,
    f16_t* __restrict__ qwF, f16_t* __restrict__ kwF,
    f16_t* __restrict__ vwF) {
  constexpr int M = kN, N = 3 * kC, K = kC;
  __shared__ __align__(16) f16_t As[4][128][8];
  __shared__ __align__(16) f16_t Bs[4][128][8];

  const int t = threadIdx.x;
  const int lane = t & 63;
  const int wid = t >> 6;
  const int wr = wid >> 1, wc = wid & 1;
  const int l15 = lane & 15, lk = lane >> 4;
  const int row0 = blockIdx.y * 128, col0 = blockIdx.x * 128;

  f32x4 acc[4][4];
#pragma unroll
  for (int i = 0; i < 4; ++i)
#pragma unroll
    for (int j = 0; j < 4; ++j) acc[i][j] = (f32x4){0.f, 0.f, 0.f, 0.f};

  for (int k0 = 0; k0 < K; k0 += 32) {
    const int kq = k0 >> 3;
#pragma unroll
    for (int s = 0; s < 2; ++s) {
      const int li = s * 256 + t;
      const int kc = li >> 7;
      const int r = li & 127;
      const size_t goff = (size_t)(kq + kc);
      char* adst = (char*)(&As[0][0][0]) + (size_t)(s * 256 + wid * 64) * 16;
      char* bdst = (char*)(&Bs[0][0][0]) + (size_t)(s * 256 + wid * 64) * 16;
      gload16(&A[(goff * M + row0 + r) * 8], adst);
      gload16(&B[(goff * N + col0 + r) * 8], bdst);
    }
    __syncthreads();

    f16x8 af[4], bf[4];
#pragma unroll
    for (int f = 0; f < 4; ++f) {
      af[f] = *(const f16x8*)&As[lk][wr * 64 + f * 16 + l15][0];
      bf[f] = *(const f16x8*)&Bs[lk][wc * 64 + f * 16 + l15][0];
    }
#pragma unroll
    for (int mf = 0; mf < 4; ++mf)
#pragma unroll
      for (int nf = 0; nf < 4; ++nf)
        acc[mf][nf] = __builtin_amdgcn_mfma_f32_16x16x32_f16(
            af[mf], bf[nf], acc[mf][nf], 0, 0, 0);
    __syncthreads();
  }

  // ---- fused epilogue ----
  const int cb = col0 + wc * 64;      // wave's global col base (0..3008)
  const int tsel = cb >> 10;          // 0=q 1=k 2=v (wave-uniform)
  const int h = (cb >> 6) & 15;       // head (wave-uniform)
  f16_t* obase = (tsel == 0 ? qwF : (tsel == 1 ? kwF : vwF));

  float bv[4], gv[4], freq[4];
  int axis[4];
#pragma unroll
  for (int nf = 0; nf < 4; ++nf) {
    bv[nf] = bias[cb + nf * 16 + l15];
    gv[nf] = (tsel == 0) ? qg[h * kD + nf * 16 + l15]
             : (tsel == 1) ? kg[h * kD + nf * 16 + l15] : 1.f;
    const int j = nf * 8 + (l15 >> 1);        // rope pair index 0..31
    axis[nf] = (j >= 10) + (j >= 20);
    freq[nf] = (j < 30)
                   ? expf(-(float)(j - axis[nf] * 10) * 0.92103403719761836f)
                   : 0.f;
  }
  const float sgn = (l15 & 1) ? 1.f : -1.f;   // rope: -sin (re) / +sin (im)

#pragma unroll
  for (int mf = 0; mf < 4; ++mf)
#pragma unroll
    for (int r = 0; r < 4; ++r) {
      const int row = row0 + wr * 64 + mf * 16 + lk * 4 + r;
      const int4 cc = *(const int4*)&coords[row * 4];  // (0,z,y,x)
      const int w = ((cc.y >> 3) * 2 + (cc.z >> 3)) * 2 + (cc.w >> 3);
      const int p = ((cc.y & 7) * 8 + (cc.z & 7)) * 8 + (cc.w & 7);
      f16_t* ob = obase + (size_t)(w * kH + h) * 32768;

      float v[4];
#pragma unroll
      for (int nf = 0; nf < 4; ++nf) v[nf] = acc[mf][nf][r] + bv[nf];

      if (tsel < 2) {
        // RMS norm over the 64-col head (reduce across nf + 16-lane group)
        float s = v[0] * v[0] + v[1] * v[1] + v[2] * v[2] + v[3] * v[3];
        s += __shfl_xor(s, 1);
        s += __shfl_xor(s, 2);
        s += __shfl_xor(s, 4);
        s += __shfl_xor(s, 8);
        const float sc = 8.0f / fmaxf(sqrtf(s), 1e-12f);  // sqrt(D)=8
#pragma unroll
        for (int nf = 0; nf < 4; ++nf) v[nf] *= sc * gv[nf];
        // RoPE (partner col differs in lane bit0)
#pragma unroll
        for (int nf = 0; nf < 4; ++nf) {
          const float c =
              (float)(axis[nf] == 0 ? cc.y : (axis[nf] == 1 ? cc.z : cc.w));
          const float ang = c * freq[nf];
          float sn, cs;
          __sincosf(ang, &sn, &cs);
          const float partner = __shfl_xor(v[nf], 1);
          v[nf] = v[nf] * cs + sgn * sn * partner;
        }
        const float qsc = (tsel == 0) ? 0.125f : 1.f;  // fold 1/sqrt(D)
#pragma unroll
        for (int nf = 0; nf < 4; ++nf) {
          const int d = nf * 16 + l15;
          ob[((d >> 3) * kL + p) * 8 + (d & 7)] = (f16_t)(v[nf] * qsc);
        }
      } else {
#pragma unroll
        for (int nf = 0; nf < 4; ++nf) {
          const int d = nf * 16 + l15;
          ob[((p >> 3) * kD + d) * 8 + (p & 7)] = (f16_t)v[nf];
        }
      }
    }
}

// ---------------------------------------------------------------------------
// Windowed attention via fp16 MFMA (f32 accum, online softmax). Verified r10.
// ---------------------------------------------------------------------------
__global__ __launch_bounds__(256) void attn_mfma(
    const f16_t* __restrict__ qw, const f16_t* __restrict__ kw,
    const f16_t* __restrict__ vw, f16_t* __restrict__ ob) {
  __shared__ __align__(16) f16_t Ks[8 * 64 * 8];  // [kq][c][8]
  __shared__ __align__(16) f16_t Vs[8 * 64 * 8];  // [ck][d][8]
  __shared__ __align__(16) f16_t Ps[4][32][72];   // per-wave P buffer

  const int bid = blockIdx.x;
  const int qt = bid & 3;
  const int h = (bid >> 2) & 15;
  const int w = bid >> 6;
  const int t = threadIdx.x;
  const int lane = t & 63;
  const int wid = t >> 6;
  const int l15 = lane & 15, lk = lane >> 4;
  const int whq = w * kH + h;
  const f16_t* qbase = qw + (size_t)whq * 32768;
  const f16_t* kbase = kw + (size_t)whq * 32768;
  const f16_t* vbase = vw + (size_t)whq * 32768;

  const int qrow0 = qt * 128 + wid * 32;

  f16x8 aq[2][2];
#pragma unroll
  for (int m = 0; m < 2; ++m)
#pragma unroll
    for (int ks = 0; ks < 2; ++ks)
      aq[m][ks] = *(const f16x8*)&qbase[((ks * 4 + lk) * kL + qrow0 +
                                         m * 16 + l15) * 8];

  f32x4 oacc[2][4];
  float mrun[2][4], lrun[2][4];
#pragma unroll
  for (int m = 0; m < 2; ++m)
#pragma unroll
    for (int i = 0; i < 4; ++i) {
      mrun[m][i] = -1e30f;
      lrun[m][i] = 0.f;
    }
#pragma unroll
  for (int m = 0; m < 2; ++m)
#pragma unroll
    for (int nf = 0; nf < 4; ++nf) oacc[m][nf] = (f32x4){0.f, 0.f, 0.f, 0.f};

  for (int kt = 0; kt < 8; ++kt) {
    __syncthreads();
#pragma unroll
    for (int s = 0; s < 2; ++s) {
      const int idx = s * 256 + t;
      const int bidx = s * 256 + wid * 64;
      gload16(&kbase[((idx >> 6) * kL + kt * 64 + (idx & 63)) * 8],
              (char*)Ks + (size_t)bidx * 16);
      gload16(&vbase[((kt * 8 + (idx >> 6)) * 64 + (idx & 63)) * 8],
              (char*)Vs + (size_t)bidx * 16);
    }
    __syncthreads();

    f32x4 sacc[2][4];
#pragma unroll
    for (int m = 0; m < 2; ++m)
#pragma unroll
      for (int nf = 0; nf < 4; ++nf) sacc[m][nf] = (f32x4){0.f, 0.f, 0.f, 0.f};
#pragma unroll
    for (int ks = 0; ks < 2; ++ks) {
      f16x8 bk[4];
#pragma unroll
      for (int nf = 0; nf < 4; ++nf)
        bk[nf] = *(const f16x8*)&Ks[((ks * 4 + lk) * 64 + nf * 16 + l15) * 8];
#pragma unroll
      for (int m = 0; m < 2; ++m)
#pragma unroll
        for (int nf = 0; nf < 4; ++nf)
          sacc[m][nf] = __builtin_amdgcn_mfma_f32_16x16x32_f16(
              aq[m][ks], bk[nf], sacc[m][nf], 0, 0, 0);
    }

#pragma unroll
    for (int m = 0; m < 2; ++m)
#pragma unroll
      for (int i = 0; i < 4; ++i) {
        float rmax = fmaxf(fmaxf(sacc[m][0][i], sacc[m][1][i]),
                           fmaxf(sacc[m][2][i], sacc[m][3][i]));
        rmax = fmaxf(rmax, __shfl_xor(rmax, 1));
        rmax = fmaxf(rmax, __shfl_xor(rmax, 2));
        rmax = fmaxf(rmax, __shfl_xor(rmax, 4));
        rmax = fmaxf(rmax, __shfl_xor(rmax, 8));
        const float mn = fmaxf(mrun[m][i], rmax);
        const float corr = __expf(mrun[m][i] - mn);
        mrun[m][i] = mn;
        float p[4];
        float rs = 0.f;
#pragma unroll
        for (int nf = 0; nf < 4; ++nf) {
          p[nf] = __expf(sacc[m][nf][i] - mn);
          rs += p[nf];
        }
        rs += __shfl_xor(rs, 1);
        rs += __shfl_xor(rs, 2);
        rs += __shfl_xor(rs, 4);
        rs += __shfl_xor(rs, 8);
        lrun[m][i] = lrun[m][i] * corr + rs;
#pragma unroll
        for (int nf = 0; nf < 4; ++nf) oacc[m][nf][i] *= corr;
        const int row = m * 16 + lk * 4 + i;
#pragma unroll
        for (int nf = 0; nf < 4; ++nf)
          Ps[wid][row][nf * 16 + l15] = (f16_t)p[nf];
      }

#pragma unroll
    for (int ks = 0; ks < 2; ++ks) {
      f16x8 pa[2], bvv[4];
#pragma unroll
      for (int m = 0; m < 2; ++m)
        pa[m] = *(const f16x8*)&Ps[wid][m * 16 + l15][ks * 32 + lk * 8];
#pragma unroll
      for (int nf = 0; nf < 4; ++nf)
        bvv[nf] = *(const f16x8*)&Vs[((ks * 4 + lk) * 64 + nf * 16 + l15) * 8];
#pragma unroll
      for (int m = 0; m < 2; ++m)
#pragma unroll
        for (int nf = 0; nf < 4; ++nf)
          oacc[m][nf] = __builtin_amdgcn_mfma_f32_16x16x32_f16(
              pa[m], bvv[nf], oacc[m][nf], 0, 0, 0);
    }
  }

  const int wz = w >> 2, wy = (w >> 1) & 1, wx = w & 1;
#pragma unroll
  for (int m = 0; m < 2; ++m)
#pragma unroll
    for (int i = 0; i < 4; ++i) {
      const int pg = qrow0 + m * 16 + lk * 4 + i;
      const int pz = pg >> 6, py = (pg >> 3) & 7, px = pg & 7;
      const int n = ((wz * 8 + pz) * 16 + wy * 8 + py) * 16 + wx * 8 + px;
      const float inv = 1.0f / lrun[m][i];
#pragma unroll
      for (int nf = 0; nf < 4; ++nf) {
        const int c0 = h * kD + nf * 16 + l15;
        ob[((size_t)(c0 >> 3) * kN + n) * 8 + (c0 & 7)] =
            (f16_t)(oacc[m][nf][i] * inv);
      }
    }
}

}  // namespace

extern "C" void kernel_launch(void* const* d_in, const int* in_sizes, int n_in,
                              void* d_out, int out_size, void* d_ws,
                              size_t ws_size, hipStream_t stream) {
  const float* x = (const float*)d_in[0];
  const int* coords = (const int*)d_in[1];
  const float* w_qkv = (const float*)d_in[2];
  const float* b_qkv = (const float*)d_in[3];
  const float* qg = (const float*)d_in[4];
  const float* kg = (const float*)d_in[5];
  const float* w_out = (const float*)d_in[6];
  const float* b_out = (const float*)d_in[7];
  float* out = (float*)d_out;

  char* ws8 = (char*)d_ws;
  f16_t* AF = (f16_t*)ws8;                         // 8 MB
  f16_t* BqF = (f16_t*)(ws8 + 8388608);            // 6 MB
  f16_t* BoF = (f16_t*)(ws8 + 16777216);           // 2 MB
  f16_t* qwF = (f16_t*)(ws8 + 33554432);           // 8 MB
  f16_t* kwF = (f16_t*)(ws8 + 41943040);           // 8 MB
  f16_t* vwF = (f16_t*)(ws8 + 50331648);           // 8 MB
  f16_t* obF = (f16_t*)(ws8 + 58720256);           // 8 MB

  // 1) pack inputs to fp16 (k-major); all three are independent
  pack_rows_f16<<<dim3(kN / 64, kC / 64), 256, 0, stream>>>(x, AF, kN, kC);
  pack_w_f16<<<dim3(3 * kC / 256, kC / 8), 256, 0, stream>>>(w_qkv, BqF, kC,
                                                             3 * kC);
  pack_w_f16<<<dim3(kC / 256, kC / 8), 256, 0, stream>>>(w_out, BoF, kC, kC);
  // 2) QKV projection with fused bias+norm+RoPE+permute epilogue
  gemm_qkv<<<dim3(3 * kC / 128, kN / 128), 256, 0, stream>>>(
      AF, BqF, b_qkv, coords, qg, kg, qwF, kwF, vwF);
  // 3) windowed attention (fp16 MFMA), writes fp16 packed O
  attn_mfma<<<dim3(4 * kH * 8), 256, 0, stream>>>(qwF, kwF, vwF, obF);
  // 4) output projection (fp16 MFMA, fp32 out + bias)
  gemm_f16<<<dim3(kC / 128, kN / 128), 256, 0, stream>>>(
      obF, BoF, b_out, out, kN, kC, kC);
}